// Round 10
// baseline (508.065 us; speedup 1.0000x reference)
//
#include <hip/hip_runtime.h>
#include <hip/hip_bf16.h>

typedef __bf16 bf16x8 __attribute__((ext_vector_type(8)));
typedef float  f32x4  __attribute__((ext_vector_type(4)));

#define MFMA(a,b,c) __builtin_amdgcn_mfma_f32_16x16x32_bf16((a),(b),(c),0,0,0)

// problem constants
#define NN_  42
#define E_   41
#define FB_  4096
#define SCALE_ 0.17677669529663687f  // 1/sqrt(32)

// ws layout, element offsets into __bf16* ws (layouts preserved == MFMA B-operand layout)
#define WB_WIN  0         // [128][32]
#define WB_QKV  4096      // [L][384][128]
#define WB_AO   102400    // [L][128][128]
#define WB_FF1  135168    // [L][256][128]
#define WB_FF2  200704    // [L][128][256]
#define WB_WOUT 266240    // [128][5376]
#define WB_X    954368    // [4096][5376] staged x_final (bf16)
#define PREP_N  954368

// smem layout (bytes), total 40704 — 4 blocks/CU (4 x 40960 = 163840 exactly).
// Register ledger (r0-r9): at (256,4) allocator reserves ~64 for acc side -> arch cap
// 64; persistent arch was res24+vp12+frag/addr ~75-85 -> spill (r5/r6/r9). THIS round
// deletes res[24]: attention output o no longer aliases xbf (goes to obf2 = dead
// wave-0/1 qk area post-PV), so residual x is RELOADED from xbf (bf16) at attn-out/FF2.
// Est arch ~50-60 <= 64 -> (256,4) fits. Also: post-qkv barrier removed (scores/
// softmax/PV wave-private; first barrier now pre-obf2-write). Precision: residual adds
// now bf16-rounded (~0.4% rel); revert to r8 config if absmax gate fails.
//  [0,27648)      per-wave qk[48][72] (q cols 0..31, k cols 32..63), w*6912
//                 aliases (lifetime-disjoint):
//                   fbf [48][40]           @0      (init/embed only)
//                   bits int[48][4]        @3840   (init/embed only; pos as bitmask)
//                   adj int[123]           @4608   (init only)
//                   depth int[48]          @5104   (init only)
//                   P_lds [48][48] bf16    @w*6912 (post-scores: qk dead; PV A-operand)
//                   obf2 [48][136] bf16    @0      (post-PV-barrier: attn-out A-operand)
//                   hbf [48][264]          @0      (FF only; 25344 B)
//                   part float[384]        @25344  (ln_update only; wave-3 P is below)
//                   statsA/B float[48]     @26880/27072
//  [27648,40704)  xbf [48][136] bf16 (x only — never aliased by o anymore)
#define SM_SZ 40704

// ---------------- weight cast to bf16 ----------------
__global__ void prep_bf16(const float* __restrict__ W_in, const float* __restrict__ qkv_w,
                          const float* __restrict__ ao_w, const float* __restrict__ ff1_w,
                          const float* __restrict__ ff2_w, const float* __restrict__ W_out,
                          __bf16* __restrict__ wb) {
  int i = blockIdx.x * 256 + threadIdx.x;
  float v;
  if      (i < 4096)   v = W_in[i];
  else if (i < 102400) v = qkv_w[i - 4096];
  else if (i < 135168) v = ao_w[i - 102400];
  else if (i < 200704) v = ff1_w[i - 135168];
  else if (i < 266240) v = ff2_w[i - 200704];
  else if (i < 954368) v = W_out[i - 266240];
  else return;
  wb[i] = (__bf16)v;
}

__device__ __forceinline__ bf16x8 ld8(const __bf16* p) { return *(const bf16x8*)p; }

__device__ __forceinline__ int pack2(float a, float b) {
  union { __bf16 h[2]; int i; } u;
  u.h[0] = (__bf16)a; u.h[1] = (__bf16)b;
  return u.i;
}

// C = A[48xK] * B^T for NB column-tiles; A in LDS (lda halfwords), B rows contiguous-k (global).
template <int NB, int KS>
__device__ __forceinline__ void gemm3xN(const __bf16* A, int lda, const __bf16* const (&B)[NB],
                                        int c16, int quad, f32x4 (&acc)[NB][3]) {
#pragma unroll
  for (int i = 0; i < NB; ++i) {
    acc[i][0] = f32x4{0,0,0,0}; acc[i][1] = f32x4{0,0,0,0}; acc[i][2] = f32x4{0,0,0,0};
  }
#pragma unroll
  for (int ks = 0; ks < KS; ++ks) {
    int ko = ks * 32 + quad * 8;
    bf16x8 a0 = ld8(A + c16 * lda + ko);
    bf16x8 a1 = ld8(A + (16 + c16) * lda + ko);
    bf16x8 a2 = ld8(A + (32 + c16) * lda + ko);
#pragma unroll
    for (int i = 0; i < NB; ++i) {
      bf16x8 b = ld8(B[i] + ko);
      acc[i][0] = MFMA(a0, b, acc[i][0]);
      acc[i][1] = MFMA(a1, b, acc[i][1]);
      acc[i][2] = MFMA(a2, b, acc[i][2]);
    }
  }
}

// LayerNorm; res in C-layout (cols (2w+nt)*16+c16); writes xbf (res is consumed). 3 barriers.
__device__ __forceinline__ void ln_update(float (&res)[3][2][4], const float* __restrict__ g,
                                          const float* __restrict__ bb, __bf16* xbf, float* part,
                                          float* statsA, float* statsB, int tid, int w, int c16,
                                          int quad) {
#pragma unroll
  for (int mt = 0; mt < 3; ++mt)
#pragma unroll
    for (int r = 0; r < 4; ++r) {
      float s = res[mt][0][r] + res[mt][1][r];
      float ss = res[mt][0][r] * res[mt][0][r] + res[mt][1][r] * res[mt][1][r];
      s += __shfl_xor(s, 1); ss += __shfl_xor(ss, 1);
      s += __shfl_xor(s, 2); ss += __shfl_xor(ss, 2);
      s += __shfl_xor(s, 4); ss += __shfl_xor(ss, 4);
      s += __shfl_xor(s, 8); ss += __shfl_xor(ss, 8);
      if (c16 == 0) {
        int row = mt * 16 + quad * 4 + r;
        part[(w * 48 + row) * 2] = s; part[(w * 48 + row) * 2 + 1] = ss;
      }
    }
  __syncthreads();
  if (tid < 48) {
    float S = 0.f, SS = 0.f;
#pragma unroll
    for (int w2 = 0; w2 < 4; ++w2) { S += part[(w2 * 48 + tid) * 2]; SS += part[(w2 * 48 + tid) * 2 + 1]; }
    float mu = S * 0.0078125f;
    float var = fmaxf(SS * 0.0078125f - mu * mu, 0.f);
    statsA[tid] = mu; statsB[tid] = rsqrtf(var + 1e-5f);
  }
  __syncthreads();
  float gg[2], bv[2];
#pragma unroll
  for (int nt = 0; nt < 2; ++nt) { int col = (2 * w + nt) * 16 + c16; gg[nt] = g[col]; bv[nt] = bb[col]; }
#pragma unroll
  for (int mt = 0; mt < 3; ++mt)
#pragma unroll
    for (int r = 0; r < 4; ++r) {
      int row = mt * 16 + quad * 4 + r;
      float mu = statsA[row], rs = statsB[row];
#pragma unroll
      for (int nt = 0; nt < 2; ++nt) {
        float v = (res[mt][nt][r] - mu) * rs * gg[nt] + bv[nt];
        xbf[row * 136 + (2 * w + nt) * 16 + c16] = (__bf16)(row < NN_ ? v : 0.f);
      }
    }
  __syncthreads();
}

// ---------------- per-tree fused encoder: wave-private attention ----------------
__global__ __launch_bounds__(256, 4) void tree_enc(
    const float* __restrict__ forest, const int* __restrict__ adjacency,
    const int* __restrict__ node_order, const float* __restrict__ b_in,
    const float* __restrict__ qkv_b, const float* __restrict__ ao_b,
    const float* __restrict__ ff1_b, const float* __restrict__ ff2_b,
    const float* __restrict__ ln1_g, const float* __restrict__ ln1_b,
    const float* __restrict__ ln2_g, const float* __restrict__ ln2_b,
    const __bf16* __restrict__ wb, __bf16* __restrict__ Xg) {
  const int f = blockIdx.x, tid = threadIdx.x;
  const int lane = tid & 63, w = tid >> 6, c16 = lane & 15, quad = lane >> 4;

  __shared__ alignas(16) unsigned char smem[SM_SZ];
  __bf16* qk     = (__bf16*)(smem + w * 6912);  // per-wave [48][72]: q cols 0..31, k cols 32..63
  __bf16* fbf    = (__bf16*)smem;               // [48][40] (init only)
  __bf16* obf2   = (__bf16*)smem;               // [48][136] attn-o (post-PV barrier)
  __bf16* hbf    = (__bf16*)smem;               // [48][264] (FF only)
  int*    bits_s = (int*)(smem + 3840);         // [48][4] pos bitmask (init/embed only)
  int*    adj_s  = (int*)(smem + 4608);
  int*    depth_s= (int*)(smem + 5104);
  float*  part   = (float*)(smem + 25344);      // ln_update only
  float*  statsA = (float*)(smem + 26880);
  float*  statsB = (float*)(smem + 27072);
  __bf16* xbf    = (__bf16*)(smem + 27648);     // [48][136] x (never aliased)

  // ---- init phase 1: zeros (fbf + bits), adjacency, depths ----
  for (int i = tid; i < 1152; i += 256) ((int*)smem)[i] = 0;  // fbf [0,3840) + bits [3840,4608)
  if (tid < E_ * 3) adj_s[tid] = adjacency[f * (E_ * 3) + tid];
  if (w == 1) {
    int v = (lane < NN_) ? node_order[f * NN_ + lane] : 0;
    int mx = v;
#pragma unroll
    for (int m = 1; m < 64; m <<= 1) mx = max(mx, __shfl_xor(mx, m));
    if (lane < 48) depth_s[lane] = (lane < NN_) ? (mx - v) : 0;
  }
  __syncthreads();

  // ---- init phase 2: stage forest bf16 + positional walk (bitmask, by depth level) ----
  for (int i = tid; i < NN_ * 32; i += 256) {
    int r = i >> 5, c = i & 31;
    fbf[r * 40 + c] = (__bf16)forest[f * (NN_ * 32) + i];
  }
  if (w == 0) {
    int pl = -1, cl = 0, pd = 0, idx = 0;
    if (lane < E_) {
      int p = adj_s[lane * 3], c = adj_s[lane * 3 + 1], s = adj_s[lane * 3 + 2];
      if (p >= 0 && c >= 0) {
        pl = p - f * NN_; cl = c - f * NN_;
        int si = s + 1; si = si < 0 ? 0 : (si > 2 ? 2 : si);
        pd = depth_s[pl]; idx = pd * 3 + si;
      }
    }
    int dv = (lane < NN_) ? depth_s[lane] : 0;
#pragma unroll
    for (int m = 1; m < 64; m <<= 1) dv = max(dv, __shfl_xor(dv, m));
    int plc = pl < 0 ? 0 : pl;
    int bm = 1 << (idx & 31), wi = idx >> 5;
    int m0 = (wi == 0) ? bm : 0, m1 = (wi == 1) ? bm : 0;
    int m2 = (wi == 2) ? bm : 0, m3 = (wi == 3) ? bm : 0;
    for (int d = 0; d < dv; ++d) {
      int4 pb = *(int4*)&bits_s[plc * 4];
      if (pl >= 0 && pd == d) {
        int4 nb;
        nb.x = pb.x | m0; nb.y = pb.y | m1; nb.z = pb.z | m2; nb.w = pb.w | m3;
        *(int4*)&bits_s[cl * 4] = nb;
      }
      asm volatile("s_waitcnt lgkmcnt(0)" ::: "memory");
    }
  }
  __syncthreads();

  // ---- embed: x0 = forest @ W_in^T + b_in + pos -> xbf only (no register residual) ----
  {
    const __bf16* Bw[2] = { wb + WB_WIN + ((2 * w) * 16 + c16) * 32,
                            wb + WB_WIN + ((2 * w + 1) * 16 + c16) * 32 };
    f32x4 ea[2][3];
    gemm3xN<2, 1>(fbf, 40, Bw, c16, quad, ea);
#pragma unroll
    for (int nt = 0; nt < 2; ++nt) {
      int col = (2 * w + nt) * 16 + c16;
      float bi = b_in[col];
      int wsel = col >> 5, shv = col & 31;
#pragma unroll
      for (int mt = 0; mt < 3; ++mt)
#pragma unroll
        for (int r = 0; r < 4; ++r) {
          int row = mt * 16 + quad * 4 + r;
          float v = ea[nt][mt][r] + bi + (float)((bits_s[row * 4 + wsel] >> shv) & 1);
          xbf[row * 136 + col] = (__bf16)(row < NN_ ? v : 0.f);
        }
    }
  }
  __syncthreads();

  // ---- encoder layers ----
  for (int l = 0; l < 2; ++l) {
    // === per-wave qkv GEMM, head h = w; three 2-tile passes (Q, K, V) ===
    int vp[2][3][2];  // [s = d-half][node m-tile][node pair]: V[mt*16+quad*4+2h..+1][s*16+c16]
    {
      const __bf16* qkvW = wb + WB_QKV + l * 384 * 128;
      const float* qbl = qkv_b + l * 384;
#pragma unroll
      for (int p = 0; p < 3; ++p) {  // 0=Q, 1=K, 2=V
        f32x4 qa[2][3];
#pragma unroll
        for (int j = 0; j < 2; ++j) { qa[j][0] = f32x4{0,0,0,0}; qa[j][1] = f32x4{0,0,0,0}; qa[j][2] = f32x4{0,0,0,0}; }
        const __bf16* Bp[2];
#pragma unroll
        for (int j = 0; j < 2; ++j)
          Bp[j] = qkvW + (p * 128 + w * 32 + j * 16 + c16) * 128;
#pragma unroll
        for (int ks = 0; ks < 4; ++ks) {
          int ko = ks * 32 + quad * 8;
          bf16x8 a0 = ld8(xbf + c16 * 136 + ko);
          bf16x8 a1 = ld8(xbf + (16 + c16) * 136 + ko);
          bf16x8 a2 = ld8(xbf + (32 + c16) * 136 + ko);
#pragma unroll
          for (int j = 0; j < 2; ++j) {
            bf16x8 b = ld8(Bp[j] + ko);
            qa[j][0] = MFMA(a0, b, qa[j][0]);
            qa[j][1] = MFMA(a1, b, qa[j][1]);
            qa[j][2] = MFMA(a2, b, qa[j][2]);
          }
        }
#pragma unroll
        for (int j = 0; j < 2; ++j) {
          float bias = qbl[p * 128 + w * 32 + j * 16 + c16];
#pragma unroll
          for (int mt = 0; mt < 3; ++mt) {
            if (p == 2) {  // V -> registers (bf16 pair-packed)
              vp[j][mt][0] = pack2(qa[j][mt][0] + bias, qa[j][mt][1] + bias);
              vp[j][mt][1] = pack2(qa[j][mt][2] + bias, qa[j][mt][3] + bias);
            } else {       // Q (scaled) / K -> qk[node][col] (wave-private LDS)
              int colo = (p == 0 ? 0 : 32) + j * 16 + c16;
#pragma unroll
              for (int r = 0; r < 4; ++r) {
                float v = qa[j][mt][r] + bias;
                if (p == 0) v *= SCALE_;
                qk[(mt * 16 + quad * 4 + r) * 72 + colo] = (__bf16)v;
              }
            }
          }
        }
      }
    }
    // NO barrier: scores/softmax/PV touch only wave-private qk + registers.

    // === scores S^T = K Q^T, 9 tiles in-register ===
    f32x4 st[3][3];
    {
      bf16x8 ka[3], qb2[3];
#pragma unroll
      for (int m = 0; m < 3; ++m) ka[m] = ld8(qk + (m * 16 + c16) * 72 + 32 + quad * 8);
#pragma unroll
      for (int n = 0; n < 3; ++n) qb2[n] = ld8(qk + (n * 16 + c16) * 72 + quad * 8);
#pragma unroll
      for (int m = 0; m < 3; ++m)
#pragma unroll
        for (int n = 0; n < 3; ++n) {
          f32x4 z{0,0,0,0};
          st[m][n] = MFMA(ka[m], qb2[n], z);
        }
    }

    // === softmax in-register -> P to LDS (qk region dead post-scores) ===
    // P_lds[q][key] bf16, stride 48 hw; thread (c16,quad) holds S^T[key=m*16+quad*4+r]
    // [q=n*16+c16] -> one b64 write per (n,m). (r9-verified, same-wave DS order.)
#pragma unroll
    for (int n = 0; n < 3; ++n) {
      float mx = -3.0e38f;
#pragma unroll
      for (int m = 0; m < 3; ++m)
#pragma unroll
        for (int r = 0; r < 4; ++r) {
          bool valid = (m < 2) || (quad * 4 + r < 10);  // key < 42
          mx = fmaxf(mx, valid ? st[m][n][r] : -3.0e38f);
        }
      mx = fmaxf(mx, __shfl_xor(mx, 16));
      mx = fmaxf(mx, __shfl_xor(mx, 32));
      float sm = 0.f, ev[3][4];
#pragma unroll
      for (int m = 0; m < 3; ++m)
#pragma unroll
        for (int r = 0; r < 4; ++r) {
          bool valid = (m < 2) || (quad * 4 + r < 10);
          float e = valid ? __expf(st[m][n][r] - mx) : 0.f;
          ev[m][r] = e; sm += e;
        }
      sm += __shfl_xor(sm, 16);
      sm += __shfl_xor(sm, 32);
      float inv = 1.f / sm;
#pragma unroll
      for (int m = 0; m < 3; ++m) {
        int2 pw;
        pw.x = pack2(ev[m][0] * inv, ev[m][1] * inv);
        pw.y = pack2(ev[m][2] * inv, ev[m][3] * inv);
        *(int2*)(qk + (n * 16 + c16) * 48 + m * 16 + quad * 4) = pw;
      }
    }

    // === PV: A = P from LDS (b128), V^T via vp shuffle-transpose ===
    f32x4 ov[3][2];
#pragma unroll
    for (int mtq = 0; mtq < 3; ++mtq) { ov[mtq][0] = f32x4{0,0,0,0}; ov[mtq][1] = f32x4{0,0,0,0}; }
    const bf16x8 zero8 = {0, 0, 0, 0, 0, 0, 0, 0};
#pragma unroll
    for (int ks = 0; ks < 2; ++ks) {
      bf16x8 bv[2];
#pragma unroll
      for (int nt = 0; nt < 2; ++nt) {
        union { int i[4]; bf16x8 v; } U;
#pragma unroll
        for (int m = 0; m < 4; ++m) {
          int srcl = (((quad << 1) + (m >> 1)) & 3) * 16 + c16;
          if (ks == 0) {
            int x0 = __shfl(vp[nt][0][m & 1], srcl);
            int x1 = __shfl(vp[nt][1][m & 1], srcl);
            U.i[m] = (quad >> 1) ? x1 : x0;
          } else {
            U.i[m] = __shfl(vp[nt][2][m & 1], srcl);
          }
        }
        bv[nt] = U.v;
      }
      bool zeroA = (ks == 1) && (quad > 1);
      int koA = zeroA ? 32 : (32 * ks + quad * 8);
#pragma unroll
      for (int mtq = 0; mtq < 3; ++mtq) {
        bf16x8 av = ld8(qk + (mtq * 16 + c16) * 48 + koA);
        if (zeroA) av = zero8;
        ov[mtq][0] = MFMA(av, bv[0], ov[mtq][0]);
        ov[mtq][1] = MFMA(av, bv[1], ov[mtq][1]);
      }
    }
    __syncthreads();  // all waves' P/qk reads done -> safe to write obf2 over waves 0/1 qk
    // o write -> obf2 (separate from xbf; x survives for residual reloads)
#pragma unroll
    for (int mtq = 0; mtq < 3; ++mtq)
#pragma unroll
      for (int nt = 0; nt < 2; ++nt)
#pragma unroll
        for (int r = 0; r < 4; ++r) {
          int row = mtq * 16 + quad * 4 + r;
          obf2[row * 136 + w * 32 + nt * 16 + c16] = (__bf16)(row < NN_ ? ov[mtq][nt][r] : 0.f);
        }
    __syncthreads();

    // === attn-out + residual (x reloaded from xbf) ===
    {
      const __bf16* aoW = wb + WB_AO + l * 128 * 128;
      const __bf16* Bs[2] = { aoW + ((2 * w) * 16 + c16) * 128, aoW + ((2 * w + 1) * 16 + c16) * 128 };
      f32x4 aa[2][3];
      gemm3xN<2, 4>(obf2, 136, Bs, c16, quad, aa);
      float resT[3][2][4];
#pragma unroll
      for (int nt = 0; nt < 2; ++nt) {
        int col = (2 * w + nt) * 16 + c16;
        float ab = ao_b[l * 128 + col];
#pragma unroll
        for (int mt = 0; mt < 3; ++mt)
#pragma unroll
          for (int r = 0; r < 4; ++r) {
            int row = mt * 16 + quad * 4 + r;
            resT[mt][nt][r] = (float)xbf[row * 136 + col] + aa[nt][mt][r] + ab;
          }
      }
      ln_update(resT, ln1_g + l * 128, ln1_b + l * 128, xbf, part, statsA, statsB, tid, w, c16, quad);
    }

    // === FF1 -> hbf (relu, bf16); two 2-tile passes ===
    {
      const __bf16* f1W = wb + WB_FF1 + l * 256 * 128;
#pragma unroll
      for (int pass = 0; pass < 2; ++pass) {
        const __bf16* Bs[2] = { f1W + ((4 * w + 2 * pass) * 16 + c16) * 128,
                                f1W + ((4 * w + 2 * pass + 1) * 16 + c16) * 128 };
        f32x4 fa[2][3];
        gemm3xN<2, 4>(xbf, 136, Bs, c16, quad, fa);
#pragma unroll
        for (int j = 0; j < 2; ++j) {
          int nt = 2 * pass + j;
          int col = (4 * w + nt) * 16 + c16;
          float b1 = ff1_b[l * 256 + col];
#pragma unroll
          for (int mt = 0; mt < 3; ++mt)
#pragma unroll
            for (int r = 0; r < 4; ++r) {
              int row = mt * 16 + quad * 4 + r;
              float v = fmaxf(fa[j][mt][r] + b1, 0.f);
              hbf[row * 264 + col] = (__bf16)(row < NN_ ? v : 0.f);
            }
        }
      }
    }
    __syncthreads();

    // === FF2 + residual (x reloaded from xbf) ===
    {
      const __bf16* f2W = wb + WB_FF2 + l * 128 * 256;
      const __bf16* Bs[2] = { f2W + ((2 * w) * 16 + c16) * 256, f2W + ((2 * w + 1) * 16 + c16) * 256 };
      f32x4 fa[2][3];
      gemm3xN<2, 8>(hbf, 264, Bs, c16, quad, fa);
      float resT[3][2][4];
#pragma unroll
      for (int nt = 0; nt < 2; ++nt) {
        int col = (2 * w + nt) * 16 + c16;
        float fb2 = ff2_b[l * 128 + col];
#pragma unroll
        for (int mt = 0; mt < 3; ++mt)
#pragma unroll
          for (int r = 0; r < 4; ++r) {
            int row = mt * 16 + quad * 4 + r;
            resT[mt][nt][r] = (float)xbf[row * 136 + col] + fa[nt][mt][r] + fb2;
          }
      }
      ln_update(resT, ln2_g + l * 128, ln2_b + l * 128, xbf, part, statsA, statsB, tid, w, c16, quad);
    }
  }

  // ---- stage out: x_final (bf16) -> ws X[f][5376] ----
  {
    __bf16* Xf = Xg + (size_t)f * 5376;
    for (int c = tid; c < 672; c += 256) {
      int row = c >> 4, co = (c & 15) * 8;
      *(bf16x8*)(Xf + row * 128 + co) = ld8(xbf + row * 136 + co);
    }
  }
}

// ---------------- output projection + final LN, K split 4-way across waves ----------------
__global__ __launch_bounds__(1024) void wout_k(const __bf16* __restrict__ X,
                                               const __bf16* __restrict__ Wb,
                                               const float* __restrict__ b_out,
                                               const float* __restrict__ lnf_g,
                                               const float* __restrict__ lnf_b,
                                               float* __restrict__ out) {
  const int blk = blockIdx.x, tid = threadIdx.x;
  const int lane = tid & 63, w2 = tid >> 6, wc = w2 & 3, kh = w2 >> 2;  // wc 0..3, kh 0..3
  const int c16 = lane & 15, quad = lane >> 4;
  __shared__ float cout[64 * 132];
  f32x4 acc0{0,0,0,0}, acc1{0,0,0,0};
  const __bf16* Ar = X + (size_t)(blk * 16 + c16) * 5376 + kh * 1344;
  const __bf16* B0 = Wb + (size_t)((2 * wc) * 16 + c16) * 5376 + kh * 1344;
  const __bf16* B1 = Wb + (size_t)((2 * wc + 1) * 16 + c16) * 5376 + kh * 1344;
  // explicit 1-deep prefetch: next iteration's loads issue before current MFMAs wait
  int ko0 = quad * 8;
  bf16x8 a = ld8(Ar + ko0), b0v = ld8(B0 + ko0), b1v = ld8(B1 + ko0);
#pragma unroll 2
  for (int ks = 0; ks < 42; ++ks) {
    bf16x8 ac = a, b0c = b0v, b1c = b1v;
    int kon = (ks < 41) ? ((ks + 1) * 32 + quad * 8) : (quad * 8);
    a = ld8(Ar + kon); b0v = ld8(B0 + kon); b1v = ld8(B1 + kon);
    acc0 = MFMA(ac, b0c, acc0);
    acc1 = MFMA(ac, b1c, acc1);
  }
#pragma unroll
  for (int nt = 0; nt < 2; ++nt) {
    f32x4 av = nt ? acc1 : acc0;
#pragma unroll
    for (int r = 0; r < 4; ++r) cout[(kh * 16 + quad * 4 + r) * 132 + (2 * wc + nt) * 16 + c16] = av[r];
  }
  __syncthreads();
  if (w2 < 4) {
#pragma unroll
    for (int rr = 0; rr < 4; ++rr) {
      int row = w2 * 4 + rr;
      float v0 = cout[row * 132 + lane] + cout[(16 + row) * 132 + lane] +
                 cout[(32 + row) * 132 + lane] + cout[(48 + row) * 132 + lane] + b_out[lane];
      float v1 = cout[row * 132 + 64 + lane] + cout[(16 + row) * 132 + 64 + lane] +
                 cout[(32 + row) * 132 + 64 + lane] + cout[(48 + row) * 132 + 64 + lane] + b_out[64 + lane];
      float s = v0 + v1, ss = v0 * v0 + v1 * v1;
#pragma unroll
      for (int m = 1; m < 64; m <<= 1) { s += __shfl_xor(s, m); ss += __shfl_xor(ss, m); }
      float mu = s * 0.0078125f;
      float var = fmaxf(ss * 0.0078125f - mu * mu, 0.f);
      float rs = rsqrtf(var + 1e-5f);
      size_t o = (size_t)(blk * 16 + row) * 128;
      out[o + lane] = (v0 - mu) * rs * lnf_g[lane] + lnf_b[lane];
      out[o + 64 + lane] = (v1 - mu) * rs * lnf_g[64 + lane] + lnf_b[64 + lane];
    }
  }
}

extern "C" void kernel_launch(void* const* d_in, const int* in_sizes, int n_in,
                              void* d_out, int out_size, void* d_ws, size_t ws_size,
                              hipStream_t stream) {
  const float* forest     = (const float*)d_in[0];
  const int*   adjacency  = (const int*)d_in[1];
  const int*   node_order = (const int*)d_in[2];
  const float* W_in       = (const float*)d_in[3];
  const float* b_in       = (const float*)d_in[4];
  const float* qkv_b      = (const float*)d_in[6];
  const float* ao_b       = (const float*)d_in[8];
  const float* ff1_b      = (const float*)d_in[10];
  const float* ff2_b      = (const float*)d_in[12];
  const float* ln1_g      = (const float*)d_in[13];
  const float* ln1_b      = (const float*)d_in[14];
  const float* ln2_g      = (const float*)d_in[15];
  const float* ln2_b      = (const float*)d_in[16];
  const float* b_out      = (const float*)d_in[18];
  const float* lnf_g      = (const float*)d_in[19];
  const float* lnf_b      = (const float*)d_in[20];
  __bf16* wb = (__bf16*)d_ws;
  float* out = (float*)d_out;

  prep_bf16<<<dim3(PREP_N / 256), dim3(256), 0, stream>>>(
      W_in, (const float*)d_in[5], (const float*)d_in[7], (const float*)d_in[9],
      (const float*)d_in[11], (const float*)d_in[17], wb);
  tree_enc<<<dim3(FB_), dim3(256), 0, stream>>>(forest, adjacency, node_order, b_in, qkv_b, ao_b,
                                                ff1_b, ff2_b, ln1_g, ln1_b, ln2_g, ln2_b, wb,
                                                wb + WB_X);
  wout_k<<<dim3(FB_ / 16), dim3(1024), 0, stream>>>(wb + WB_X, wb + WB_WOUT, b_out, lnf_g, lnf_b,
                                                    out);
}

// Round 11
// 478.565 us; speedup vs baseline: 1.0616x; 1.0616x over previous
//
#include <hip/hip_runtime.h>
#include <hip/hip_bf16.h>

typedef __bf16 bf16x8 __attribute__((ext_vector_type(8)));
typedef float  f32x4  __attribute__((ext_vector_type(4)));

#define MFMA(a,b,c) __builtin_amdgcn_mfma_f32_16x16x32_bf16((a),(b),(c),0,0,0)

// problem constants
#define NN_  42
#define E_   41
#define FB_  4096
#define SCALE_ 0.17677669529663687f  // 1/sqrt(32)

// ws layout, element offsets into __bf16* ws (layouts preserved == MFMA B-operand layout)
#define WB_WIN  0         // [128][32]
#define WB_QKV  4096      // [L][384][128]
#define WB_AO   102400    // [L][128][128]
#define WB_FF1  135168    // [L][256][128]
#define WB_FF2  200704    // [L][128][256]
#define WB_WOUT 266240    // [128][5376]
#define WB_X    954368    // [4096][5376] staged x_final (bf16)
#define PREP_N  954368

// smem layout (bytes), total 40704.
// OCCUPANCY VERDICT (r0-r10): (256,4) spilled 4x (r5/r6/r9/r10) — softmax live set
// (st 36 + ev 12 + vp 12 + addr) can't fit the 64-arch-reg budget 4 waves/EU leaves.
// 3 blocks/CU is the ceiling; r8 config (VGPR 84, zero spill, 359us) is the base.
// THIS round (single variable vs r8): post-qkv barrier slides to just before the obf
// write. Hazard: qkv reads xbf cross-wave; scores/softmax/PV touch only wave-private
// qk + regs (motion validated in r9/r10); the obf write aliases xbf, so ONE barrier
// immediately before it suffices. 9 -> 8 barriers/layer + waves de-lockstep through
// the attention math. r7's regression is attributed to its ln_update rewrite (spill
// +7MB), not this motion — this isolates it.
//  [0,27648)      per-wave qk[48][72] (q cols 0..31, k cols 32..63), w*6912
//                 aliases (lifetime-disjoint):
//                   fbf [48][40]           @0      (init/embed only)
//                   bits int[48][4]        @3840   (init/embed only; pos as bitmask)
//                   adj int[123]           @4608   (init only)
//                   depth int[48]          @5104   (init only)
//                   hbf [48][264]          @0      (FF only; 25344 B)
//                   part float[384]        @25344  (ln_update only; wave-3 qk rows 32+
//                   statsA/B float[48]     @26880/27072   dead post-obf barrier)
//  [27648,40704)  xbf/obf [48][136] bf16 (aliased; the slid barrier guards the swap)
#define SM_SZ 40704

// ---------------- weight cast to bf16 ----------------
__global__ void prep_bf16(const float* __restrict__ W_in, const float* __restrict__ qkv_w,
                          const float* __restrict__ ao_w, const float* __restrict__ ff1_w,
                          const float* __restrict__ ff2_w, const float* __restrict__ W_out,
                          __bf16* __restrict__ wb) {
  int i = blockIdx.x * 256 + threadIdx.x;
  float v;
  if      (i < 4096)   v = W_in[i];
  else if (i < 102400) v = qkv_w[i - 4096];
  else if (i < 135168) v = ao_w[i - 102400];
  else if (i < 200704) v = ff1_w[i - 135168];
  else if (i < 266240) v = ff2_w[i - 200704];
  else if (i < 954368) v = W_out[i - 266240];
  else return;
  wb[i] = (__bf16)v;
}

__device__ __forceinline__ bf16x8 ld8(const __bf16* p) { return *(const bf16x8*)p; }

__device__ __forceinline__ int pack2(float a, float b) {
  union { __bf16 h[2]; int i; } u;
  u.h[0] = (__bf16)a; u.h[1] = (__bf16)b;
  return u.i;
}

// C = A[48xK] * B^T for NB column-tiles; A in LDS (lda halfwords), B rows contiguous-k (global).
template <int NB, int KS>
__device__ __forceinline__ void gemm3xN(const __bf16* A, int lda, const __bf16* const (&B)[NB],
                                        int c16, int quad, f32x4 (&acc)[NB][3]) {
#pragma unroll
  for (int i = 0; i < NB; ++i) {
    acc[i][0] = f32x4{0,0,0,0}; acc[i][1] = f32x4{0,0,0,0}; acc[i][2] = f32x4{0,0,0,0};
  }
#pragma unroll
  for (int ks = 0; ks < KS; ++ks) {
    int ko = ks * 32 + quad * 8;
    bf16x8 a0 = ld8(A + c16 * lda + ko);
    bf16x8 a1 = ld8(A + (16 + c16) * lda + ko);
    bf16x8 a2 = ld8(A + (32 + c16) * lda + ko);
#pragma unroll
    for (int i = 0; i < NB; ++i) {
      bf16x8 b = ld8(B[i] + ko);
      acc[i][0] = MFMA(a0, b, acc[i][0]);
      acc[i][1] = MFMA(a1, b, acc[i][1]);
      acc[i][2] = MFMA(a2, b, acc[i][2]);
    }
  }
}

// LayerNorm update; res in C-layout (cols (2w+nt)*16+c16); rewrites res + xbf. 3 barriers.
__device__ __forceinline__ void ln_update(float (&res)[3][2][4], const float* __restrict__ g,
                                          const float* __restrict__ bb, __bf16* xbf, float* part,
                                          float* statsA, float* statsB, int tid, int w, int c16,
                                          int quad) {
#pragma unroll
  for (int mt = 0; mt < 3; ++mt)
#pragma unroll
    for (int r = 0; r < 4; ++r) {
      float s = res[mt][0][r] + res[mt][1][r];
      float ss = res[mt][0][r] * res[mt][0][r] + res[mt][1][r] * res[mt][1][r];
      s += __shfl_xor(s, 1); ss += __shfl_xor(ss, 1);
      s += __shfl_xor(s, 2); ss += __shfl_xor(ss, 2);
      s += __shfl_xor(s, 4); ss += __shfl_xor(ss, 4);
      s += __shfl_xor(s, 8); ss += __shfl_xor(ss, 8);
      if (c16 == 0) {
        int row = mt * 16 + quad * 4 + r;
        part[(w * 48 + row) * 2] = s; part[(w * 48 + row) * 2 + 1] = ss;
      }
    }
  __syncthreads();
  if (tid < 48) {
    float S = 0.f, SS = 0.f;
#pragma unroll
    for (int w2 = 0; w2 < 4; ++w2) { S += part[(w2 * 48 + tid) * 2]; SS += part[(w2 * 48 + tid) * 2 + 1]; }
    float mu = S * 0.0078125f;
    float var = fmaxf(SS * 0.0078125f - mu * mu, 0.f);
    statsA[tid] = mu; statsB[tid] = rsqrtf(var + 1e-5f);
  }
  __syncthreads();
  float gg[2], bv[2];
#pragma unroll
  for (int nt = 0; nt < 2; ++nt) { int col = (2 * w + nt) * 16 + c16; gg[nt] = g[col]; bv[nt] = bb[col]; }
#pragma unroll
  for (int mt = 0; mt < 3; ++mt)
#pragma unroll
    for (int r = 0; r < 4; ++r) {
      int row = mt * 16 + quad * 4 + r;
      float mu = statsA[row], rs = statsB[row];
#pragma unroll
      for (int nt = 0; nt < 2; ++nt) {
        float v = (res[mt][nt][r] - mu) * rs * gg[nt] + bv[nt];
        res[mt][nt][r] = v;
        xbf[row * 136 + (2 * w + nt) * 16 + c16] = (__bf16)(row < NN_ ? v : 0.f);
      }
    }
  __syncthreads();
}

// ---------------- per-tree fused encoder: wave-private attention ----------------
__global__ __launch_bounds__(256, 3) void tree_enc(
    const float* __restrict__ forest, const int* __restrict__ adjacency,
    const int* __restrict__ node_order, const float* __restrict__ b_in,
    const float* __restrict__ qkv_b, const float* __restrict__ ao_b,
    const float* __restrict__ ff1_b, const float* __restrict__ ff2_b,
    const float* __restrict__ ln1_g, const float* __restrict__ ln1_b,
    const float* __restrict__ ln2_g, const float* __restrict__ ln2_b,
    const __bf16* __restrict__ wb, __bf16* __restrict__ Xg) {
  const int f = blockIdx.x, tid = threadIdx.x;
  const int lane = tid & 63, w = tid >> 6, c16 = lane & 15, quad = lane >> 4;

  __shared__ alignas(16) unsigned char smem[SM_SZ];
  __bf16* qk     = (__bf16*)(smem + w * 6912);  // per-wave [48][72]: q cols 0..31, k cols 32..63
  __bf16* fbf    = (__bf16*)smem;               // [48][40] (init only)
  __bf16* hbf    = (__bf16*)smem;               // [48][264] (FF only)
  int*    bits_s = (int*)(smem + 3840);         // [48][4] pos bitmask (init/embed only)
  int*    adj_s  = (int*)(smem + 4608);
  int*    depth_s= (int*)(smem + 5104);
  float*  part   = (float*)(smem + 25344);      // ln_update only (qk tail dead then)
  float*  statsA = (float*)(smem + 26880);
  float*  statsB = (float*)(smem + 27072);
  __bf16* xbf    = (__bf16*)(smem + 27648);     // [48][136] x / attn-o (aliased)

  // ---- init phase 1: zeros (fbf + bits), adjacency, depths ----
  for (int i = tid; i < 1152; i += 256) ((int*)smem)[i] = 0;  // fbf [0,3840) + bits [3840,4608)
  if (tid < E_ * 3) adj_s[tid] = adjacency[f * (E_ * 3) + tid];
  if (w == 1) {
    int v = (lane < NN_) ? node_order[f * NN_ + lane] : 0;
    int mx = v;
#pragma unroll
    for (int m = 1; m < 64; m <<= 1) mx = max(mx, __shfl_xor(mx, m));
    if (lane < 48) depth_s[lane] = (lane < NN_) ? (mx - v) : 0;
  }
  __syncthreads();

  // ---- init phase 2: stage forest bf16 + positional walk (bitmask, by depth level) ----
  for (int i = tid; i < NN_ * 32; i += 256) {
    int r = i >> 5, c = i & 31;
    fbf[r * 40 + c] = (__bf16)forest[f * (NN_ * 32) + i];
  }
  if (w == 0) {
    // one edge per lane; process levels in parallel. pos values are 0/1 at distinct
    // indices (distinct ancestor depths) => 128-bit OR mask per node == the sum.
    int pl = -1, cl = 0, pd = 0, idx = 0;
    if (lane < E_) {
      int p = adj_s[lane * 3], c = adj_s[lane * 3 + 1], s = adj_s[lane * 3 + 2];
      if (p >= 0 && c >= 0) {
        pl = p - f * NN_; cl = c - f * NN_;
        int si = s + 1; si = si < 0 ? 0 : (si > 2 ? 2 : si);
        pd = depth_s[pl]; idx = pd * 3 + si;
      }
    }
    int dv = (lane < NN_) ? depth_s[lane] : 0;
#pragma unroll
    for (int m = 1; m < 64; m <<= 1) dv = max(dv, __shfl_xor(dv, m));
    int plc = pl < 0 ? 0 : pl;
    int bm = 1 << (idx & 31), wi = idx >> 5;
    int m0 = (wi == 0) ? bm : 0, m1 = (wi == 1) ? bm : 0;
    int m2 = (wi == 2) ? bm : 0, m3 = (wi == 3) ? bm : 0;
    for (int d = 0; d < dv; ++d) {
      int4 pb = *(int4*)&bits_s[plc * 4];
      if (pl >= 0 && pd == d) {
        int4 nb;
        nb.x = pb.x | m0; nb.y = pb.y | m1; nb.z = pb.z | m2; nb.w = pb.w | m3;
        *(int4*)&bits_s[cl * 4] = nb;
      }
      asm volatile("s_waitcnt lgkmcnt(0)" ::: "memory");
    }
  }
  __syncthreads();

  // ---- embed: x0 = forest @ W_in^T + b_in + pos ----
  float res[3][2][4];
  {
    const __bf16* Bw[2] = { wb + WB_WIN + ((2 * w) * 16 + c16) * 32,
                            wb + WB_WIN + ((2 * w + 1) * 16 + c16) * 32 };
    f32x4 ea[2][3];
    gemm3xN<2, 1>(fbf, 40, Bw, c16, quad, ea);
#pragma unroll
    for (int nt = 0; nt < 2; ++nt) {
      int col = (2 * w + nt) * 16 + c16;
      float bi = b_in[col];
      int wsel = col >> 5, shv = col & 31;
#pragma unroll
      for (int mt = 0; mt < 3; ++mt)
#pragma unroll
        for (int r = 0; r < 4; ++r) {
          int row = mt * 16 + quad * 4 + r;
          float v = ea[nt][mt][r] + bi + (float)((bits_s[row * 4 + wsel] >> shv) & 1);
          res[mt][nt][r] = v;
          xbf[row * 136 + col] = (__bf16)(row < NN_ ? v : 0.f);
        }
    }
  }
  __syncthreads();

  // ---- encoder layers ----
  for (int l = 0; l < 2; ++l) {
    // === per-wave qkv GEMM, head h = w; three 2-tile passes (Q, K, V; peak acc 24) ===
    int vp[2][3][2];  // [s = d-half][node m-tile][node pair]: V[mt*16+quad*4+2h..+1][s*16+c16]
    {
      const __bf16* qkvW = wb + WB_QKV + l * 384 * 128;
      const float* qbl = qkv_b + l * 384;
#pragma unroll
      for (int p = 0; p < 3; ++p) {  // 0=Q, 1=K, 2=V
        f32x4 qa[2][3];
#pragma unroll
        for (int j = 0; j < 2; ++j) { qa[j][0] = f32x4{0,0,0,0}; qa[j][1] = f32x4{0,0,0,0}; qa[j][2] = f32x4{0,0,0,0}; }
        const __bf16* Bp[2];
#pragma unroll
        for (int j = 0; j < 2; ++j)
          Bp[j] = qkvW + (p * 128 + w * 32 + j * 16 + c16) * 128;
#pragma unroll
        for (int ks = 0; ks < 4; ++ks) {
          int ko = ks * 32 + quad * 8;
          bf16x8 a0 = ld8(xbf + c16 * 136 + ko);
          bf16x8 a1 = ld8(xbf + (16 + c16) * 136 + ko);
          bf16x8 a2 = ld8(xbf + (32 + c16) * 136 + ko);
#pragma unroll
          for (int j = 0; j < 2; ++j) {
            bf16x8 b = ld8(Bp[j] + ko);
            qa[j][0] = MFMA(a0, b, qa[j][0]);
            qa[j][1] = MFMA(a1, b, qa[j][1]);
            qa[j][2] = MFMA(a2, b, qa[j][2]);
          }
        }
#pragma unroll
        for (int j = 0; j < 2; ++j) {
          float bias = qbl[p * 128 + w * 32 + j * 16 + c16];
#pragma unroll
          for (int mt = 0; mt < 3; ++mt) {
            if (p == 2) {  // V -> registers (bf16 pair-packed), no LDS round-trip
              vp[j][mt][0] = pack2(qa[j][mt][0] + bias, qa[j][mt][1] + bias);
              vp[j][mt][1] = pack2(qa[j][mt][2] + bias, qa[j][mt][3] + bias);
            } else {       // Q (scaled) / K -> qk[node][col] (wave-private LDS)
              int colo = (p == 0 ? 0 : 32) + j * 16 + c16;
#pragma unroll
              for (int r = 0; r < 4; ++r) {
                float v = qa[j][mt][r] + bias;
                if (p == 0) v *= SCALE_;
                qk[(mt * 16 + quad * 4 + r) * 72 + colo] = (__bf16)v;
              }
            }
          }
        }
      }
    }
    // NO barrier here (slid down): scores/softmax/PV touch only wave-private qk +
    // registers. The xbf-read vs obf-write hazard is guarded by the barrier
    // immediately before the obf write below.

    // === scores S^T = K Q^T, 9 tiles in-register ===
    f32x4 st[3][3];
    {
      bf16x8 ka[3], qb2[3];
#pragma unroll
      for (int m = 0; m < 3; ++m) ka[m] = ld8(qk + (m * 16 + c16) * 72 + 32 + quad * 8);
#pragma unroll
      for (int n = 0; n < 3; ++n) qb2[n] = ld8(qk + (n * 16 + c16) * 72 + quad * 8);
#pragma unroll
      for (int m = 0; m < 3; ++m)
#pragma unroll
        for (int n = 0; n < 3; ++n) {
          f32x4 z{0,0,0,0};
          st[m][n] = MFMA(ka[m], qb2[n], z);
        }
    }

    // === softmax fully in-register (query = n-tile*16 + c16; keys on quad/reg) ===
    int dwp[3][3][2];  // packed P bf16 pairs [key-tile][query-tile][dword]
#pragma unroll
    for (int n = 0; n < 3; ++n) {
      float mx = -3.0e38f;
#pragma unroll
      for (int m = 0; m < 3; ++m)
#pragma unroll
        for (int r = 0; r < 4; ++r) {
          bool valid = (m < 2) || (quad * 4 + r < 10);  // key < 42
          mx = fmaxf(mx, valid ? st[m][n][r] : -3.0e38f);
        }
      mx = fmaxf(mx, __shfl_xor(mx, 16));
      mx = fmaxf(mx, __shfl_xor(mx, 32));
      float sm = 0.f, ev[3][4];
#pragma unroll
      for (int m = 0; m < 3; ++m)
#pragma unroll
        for (int r = 0; r < 4; ++r) {
          bool valid = (m < 2) || (quad * 4 + r < 10);
          float e = valid ? __expf(st[m][n][r] - mx) : 0.f;
          ev[m][r] = e; sm += e;
        }
      sm += __shfl_xor(sm, 16);
      sm += __shfl_xor(sm, 32);
      float inv = 1.f / sm;
#pragma unroll
      for (int m = 0; m < 3; ++m) {
        dwp[m][n][0] = pack2(ev[m][0] * inv, ev[m][1] * inv);
        dwp[m][n][1] = pack2(ev[m][2] * inv, ev[m][3] * inv);
      }
    }

    // === PV: both P and V^T fragments via shuffle-transpose (no LDS round-trip) ===
    f32x4 ov[3][2];
#pragma unroll
    for (int mtq = 0; mtq < 3; ++mtq) { ov[mtq][0] = f32x4{0,0,0,0}; ov[mtq][1] = f32x4{0,0,0,0}; }
    int sl0 = (2 * (quad & 1)) * 16 + c16, sl1 = sl0 + 16;
    bool hi = quad > 1;
#pragma unroll
    for (int ks = 0; ks < 2; ++ks) {
      // B-operand: V[g..g+7][d=nt*16+c16], g = koB(quad). dword m holds nodes (g+2m, g+2m+1):
      //   src lane = (((quad<<1)+(m>>1))&3)*16 + c16, reg = vp[nt][mt_src][m&1],
      //   mt_src = quad>>1 (ks=0) | 2 (ks=1).  Matches A-operand koB exactly (A=0 there).
      bf16x8 bv[2];
#pragma unroll
      for (int nt = 0; nt < 2; ++nt) {
        union { int i[4]; bf16x8 v; } U;
#pragma unroll
        for (int m = 0; m < 4; ++m) {
          int srcl = (((quad << 1) + (m >> 1)) & 3) * 16 + c16;
          if (ks == 0) {
            int x0 = __shfl(vp[nt][0][m & 1], srcl);
            int x1 = __shfl(vp[nt][1][m & 1], srcl);
            U.i[m] = (quad >> 1) ? x1 : x0;
          } else {
            U.i[m] = __shfl(vp[nt][2][m & 1], srcl);
          }
        }
        bv[nt] = U.v;
      }
      int lo = 2 * ks;
#pragma unroll
      for (int mtq = 0; mtq < 3; ++mtq) {
        int a0 = __shfl(dwp[lo][mtq][0], sl0), a1 = __shfl(dwp[lo][mtq][1], sl0);
        int a2 = __shfl(dwp[lo][mtq][0], sl1), a3 = __shfl(dwp[lo][mtq][1], sl1);
        int b0 = 0, b1 = 0, b2 = 0, b3 = 0;
        if (ks == 0) {
          b0 = __shfl(dwp[1][mtq][0], sl0); b1 = __shfl(dwp[1][mtq][1], sl0);
          b2 = __shfl(dwp[1][mtq][0], sl1); b3 = __shfl(dwp[1][mtq][1], sl1);
        }
        union { int i[4]; bf16x8 v; } A;
        A.i[0] = hi ? b0 : a0; A.i[1] = hi ? b1 : a1;
        A.i[2] = hi ? b2 : a2; A.i[3] = hi ? b3 : a3;
        ov[mtq][0] = MFMA(A.v, bv[0], ov[mtq][0]);
        ov[mtq][1] = MFMA(A.v, bv[1], ov[mtq][1]);
      }
    }
    __syncthreads();  // slid barrier: all waves done reading xbf (qkv) before overwrite
    // obf (= xbf alias) write: head slab cols w*32..w*32+31
#pragma unroll
    for (int mtq = 0; mtq < 3; ++mtq)
#pragma unroll
      for (int nt = 0; nt < 2; ++nt)
#pragma unroll
        for (int r = 0; r < 4; ++r) {
          int row = mtq * 16 + quad * 4 + r;
          xbf[row * 136 + w * 32 + nt * 16 + c16] = (__bf16)(row < NN_ ? ov[mtq][nt][r] : 0.f);
        }
    __syncthreads();

    // === attn-out + residual ===
    {
      const __bf16* aoW = wb + WB_AO + l * 128 * 128;
      const __bf16* Bs[2] = { aoW + ((2 * w) * 16 + c16) * 128, aoW + ((2 * w + 1) * 16 + c16) * 128 };
      f32x4 aa[2][3];
      gemm3xN<2, 4>(xbf, 136, Bs, c16, quad, aa);
#pragma unroll
      for (int nt = 0; nt < 2; ++nt) {
        float ab = ao_b[l * 128 + (2 * w + nt) * 16 + c16];
#pragma unroll
        for (int mt = 0; mt < 3; ++mt)
#pragma unroll
          for (int r = 0; r < 4; ++r) res[mt][nt][r] += aa[nt][mt][r] + ab;
      }
    }
    ln_update(res, ln1_g + l * 128, ln1_b + l * 128, xbf, part, statsA, statsB, tid, w, c16, quad);

    // === FF1 -> hbf (relu, bf16); two 2-tile passes (peak acc 24) ===
    {
      const __bf16* f1W = wb + WB_FF1 + l * 256 * 128;
#pragma unroll
      for (int pass = 0; pass < 2; ++pass) {
        const __bf16* Bs[2] = { f1W + ((4 * w + 2 * pass) * 16 + c16) * 128,
                                f1W + ((4 * w + 2 * pass + 1) * 16 + c16) * 128 };
        f32x4 fa[2][3];
        gemm3xN<2, 4>(xbf, 136, Bs, c16, quad, fa);
#pragma unroll
        for (int j = 0; j < 2; ++j) {
          int nt = 2 * pass + j;
          int col = (4 * w + nt) * 16 + c16;
          float b1 = ff1_b[l * 256 + col];
#pragma unroll
          for (int mt = 0; mt < 3; ++mt)
#pragma unroll
            for (int r = 0; r < 4; ++r) {
              int row = mt * 16 + quad * 4 + r;
              float v = fmaxf(fa[j][mt][r] + b1, 0.f);
              hbf[row * 264 + col] = (__bf16)(row < NN_ ? v : 0.f);
            }
        }
      }
    }
    __syncthreads();

    // === FF2 + residual ===
    {
      const __bf16* f2W = wb + WB_FF2 + l * 128 * 256;
      const __bf16* Bs[2] = { f2W + ((2 * w) * 16 + c16) * 256, f2W + ((2 * w + 1) * 16 + c16) * 256 };
      f32x4 fa[2][3];
      gemm3xN<2, 8>(hbf, 264, Bs, c16, quad, fa);
#pragma unroll
      for (int nt = 0; nt < 2; ++nt) {
        float fb2 = ff2_b[l * 128 + (2 * w + nt) * 16 + c16];
#pragma unroll
        for (int mt = 0; mt < 3; ++mt)
#pragma unroll
          for (int r = 0; r < 4; ++r) res[mt][nt][r] += fa[nt][mt][r] + fb2;
      }
    }
    ln_update(res, ln2_g + l * 128, ln2_b + l * 128, xbf, part, statsA, statsB, tid, w, c16, quad);
  }

  // ---- stage out: x_final (bf16) -> ws X[f][5376] ----
  {
    __bf16* Xf = Xg + (size_t)f * 5376;
    for (int c = tid; c < 672; c += 256) {
      int row = c >> 4, co = (c & 15) * 8;
      *(bf16x8*)(Xf + row * 128 + co) = ld8(xbf + row * 136 + co);
    }
  }
}

// ---------------- output projection + final LN, K split 4-way across waves ----------------
__global__ __launch_bounds__(1024) void wout_k(const __bf16* __restrict__ X,
                                               const __bf16* __restrict__ Wb,
                                               const float* __restrict__ b_out,
                                               const float* __restrict__ lnf_g,
                                               const float* __restrict__ lnf_b,
                                               float* __restrict__ out) {
  const int blk = blockIdx.x, tid = threadIdx.x;
  const int lane = tid & 63, w2 = tid >> 6, wc = w2 & 3, kh = w2 >> 2;  // wc 0..3, kh 0..3
  const int c16 = lane & 15, quad = lane >> 4;
  __shared__ float cout[64 * 132];
  f32x4 acc0{0,0,0,0}, acc1{0,0,0,0};
  const __bf16* Ar = X + (size_t)(blk * 16 + c16) * 5376 + kh * 1344;
  const __bf16* B0 = Wb + (size_t)((2 * wc) * 16 + c16) * 5376 + kh * 1344;
  const __bf16* B1 = Wb + (size_t)((2 * wc + 1) * 16 + c16) * 5376 + kh * 1344;
  // explicit 1-deep prefetch: next iteration's loads issue before current MFMAs wait
  int ko0 = quad * 8;
  bf16x8 a = ld8(Ar + ko0), b0v = ld8(B0 + ko0), b1v = ld8(B1 + ko0);
#pragma unroll 2
  for (int ks = 0; ks < 42; ++ks) {
    bf16x8 ac = a, b0c = b0v, b1c = b1v;
    int kon = (ks < 41) ? ((ks + 1) * 32 + quad * 8) : (quad * 8);
    a = ld8(Ar + kon); b0v = ld8(B0 + kon); b1v = ld8(B1 + kon);
    acc0 = MFMA(ac, b0c, acc0);
    acc1 = MFMA(ac, b1c, acc1);
  }
#pragma unroll
  for (int nt = 0; nt < 2; ++nt) {
    f32x4 av = nt ? acc1 : acc0;
#pragma unroll
    for (int r = 0; r < 4; ++r) cout[(kh * 16 + quad * 4 + r) * 132 + (2 * wc + nt) * 16 + c16] = av[r];
  }
  __syncthreads();
  if (w2 < 4) {
#pragma unroll
    for (int rr = 0; rr < 4; ++rr) {
      int row = w2 * 4 + rr;
      float v0 = cout[row * 132 + lane] + cout[(16 + row) * 132 + lane] +
                 cout[(32 + row) * 132 + lane] + cout[(48 + row) * 132 + lane] + b_out[lane];
      float v1 = cout[row * 132 + 64 + lane] + cout[(16 + row) * 132 + 64 + lane] +
                 cout[(32 + row) * 132 + 64 + lane] + cout[(48 + row) * 132 + 64 + lane] + b_out[64 + lane];
      float s = v0 + v1, ss = v0 * v0 + v1 * v1;
#pragma unroll
      for (int m = 1; m < 64; m <<= 1) { s += __shfl_xor(s, m); ss += __shfl_xor(ss, m); }
      float mu = s * 0.0078125f;
      float var = fmaxf(ss * 0.0078125f - mu * mu, 0.f);
      float rs = rsqrtf(var + 1e-5f);
      size_t o = (size_t)(blk * 16 + row) * 128;
      out[o + lane] = (v0 - mu) * rs * lnf_g[lane] + lnf_b[lane];
      out[o + 64 + lane] = (v1 - mu) * rs * lnf_g[64 + lane] + lnf_b[64 + lane];
    }
  }
}

extern "C" void kernel_launch(void* const* d_in, const int* in_sizes, int n_in,
                              void* d_out, int out_size, void* d_ws, size_t ws_size,
                              hipStream_t stream) {
  const float* forest     = (const float*)d_in[0];
  const int*   adjacency  = (const int*)d_in[1];
  const int*   node_order = (const int*)d_in[2];
  const float* W_in       = (const float*)d_in[3];
  const float* b_in       = (const float*)d_in[4];
  const float* qkv_b      = (const float*)d_in[6];
  const float* ao_b       = (const float*)d_in[8];
  const float* ff1_b      = (const float*)d_in[10];
  const float* ff2_b      = (const float*)d_in[12];
  const float* ln1_g      = (const float*)d_in[13];
  const float* ln1_b      = (const float*)d_in[14];
  const float* ln2_g      = (const float*)d_in[15];
  const float* ln2_b      = (const float*)d_in[16];
  const float* b_out      = (const float*)d_in[18];
  const float* lnf_g      = (const float*)d_in[19];
  const float* lnf_b      = (const float*)d_in[20];
  __bf16* wb = (__bf16*)d_ws;
  float* out = (float*)d_out;

  prep_bf16<<<dim3(PREP_N / 256), dim3(256), 0, stream>>>(
      W_in, (const float*)d_in[5], (const float*)d_in[7], (const float*)d_in[9],
      (const float*)d_in[11], (const float*)d_in[17], wb);
  tree_enc<<<dim3(FB_), dim3(256), 0, stream>>>(forest, adjacency, node_order, b_in, qkv_b, ao_b,
                                                ff1_b, ff2_b, ln1_g, ln1_b, ln2_g, ln2_b, wb,
                                                wb + WB_X);
  wout_k<<<dim3(FB_ / 16), dim3(1024), 0, stream>>>(wb + WB_X, wb + WB_WOUT, b_out, lnf_g, lnf_b,
                                                    out);
}

// Round 12
// 475.842 us; speedup vs baseline: 1.0677x; 1.0057x over previous
//
#include <hip/hip_runtime.h>
#include <hip/hip_bf16.h>

typedef __bf16 bf16x8 __attribute__((ext_vector_type(8)));
typedef float  f32x4  __attribute__((ext_vector_type(4)));

#define MFMA(a,b,c) __builtin_amdgcn_mfma_f32_16x16x32_bf16((a),(b),(c),0,0,0)

// problem constants
#define NN_  42
#define E_   41
#define FB_  4096
#define SCALE_ 0.17677669529663687f  // 1/sqrt(32)

// ws layout, element offsets into __bf16* ws (layouts preserved == MFMA B-operand layout)
#define WB_WIN  0         // [128][32]
#define WB_QKV  4096      // [L][384][128]
#define WB_AO   102400    // [L][128][128]
#define WB_FF1  135168    // [L][256][128]
#define WB_FF2  200704    // [L][128][256]
#define WB_WOUT 266240    // [128][5376]
#define WB_X    954368    // [4096][5376] staged x_final (bf16)
#define PREP_N  954368

// smem layout (bytes), total 40704.
// tree_enc = r11 EXACT (best verified: 359us, VGPR 84, zero spill, 32% occ; 3 blocks/CU
// register-ceiling proven by 4 failed (256,4) attempts r5/r6/r9/r10; slid post-qkv
// barrier validated r11). THIS round changes ONLY wout_k: 1-deep -> 6-deep software
// pipeline. wout_k was ~100us for 44MB HBM stream (~450 GB/s, latency-bound: 16 waves
// x 48B in flight = 0.75KB/CU vs ~2.2KB needed for 1.5TB/s). 6-deep rotating bf16x8
// buffers, fully unrolled (static indices, rule-#20 safe); ~105 VGPR < 128 hard cap of
// the 1024-thread block. Fallback if spill: depth 4.
//  [0,27648)      per-wave qk[48][72] (q cols 0..31, k cols 32..63), w*6912
//                 aliases (lifetime-disjoint):
//                   fbf [48][40]           @0      (init/embed only)
//                   bits int[48][4]        @3840   (init/embed only; pos as bitmask)
//                   adj int[123]           @4608   (init only)
//                   depth int[48]          @5104   (init only)
//                   hbf [48][264]          @0      (FF only; 25344 B)
//                   part float[384]        @25344  (ln_update only; wave-3 qk rows 32+
//                   statsA/B float[48]     @26880/27072   dead post-obf barrier)
//  [27648,40704)  xbf/obf [48][136] bf16 (aliased; the slid barrier guards the swap)
#define SM_SZ 40704

// ---------------- weight cast to bf16 ----------------
__global__ void prep_bf16(const float* __restrict__ W_in, const float* __restrict__ qkv_w,
                          const float* __restrict__ ao_w, const float* __restrict__ ff1_w,
                          const float* __restrict__ ff2_w, const float* __restrict__ W_out,
                          __bf16* __restrict__ wb) {
  int i = blockIdx.x * 256 + threadIdx.x;
  float v;
  if      (i < 4096)   v = W_in[i];
  else if (i < 102400) v = qkv_w[i - 4096];
  else if (i < 135168) v = ao_w[i - 102400];
  else if (i < 200704) v = ff1_w[i - 135168];
  else if (i < 266240) v = ff2_w[i - 200704];
  else if (i < 954368) v = W_out[i - 266240];
  else return;
  wb[i] = (__bf16)v;
}

__device__ __forceinline__ bf16x8 ld8(const __bf16* p) { return *(const bf16x8*)p; }

__device__ __forceinline__ int pack2(float a, float b) {
  union { __bf16 h[2]; int i; } u;
  u.h[0] = (__bf16)a; u.h[1] = (__bf16)b;
  return u.i;
}

// C = A[48xK] * B^T for NB column-tiles; A in LDS (lda halfwords), B rows contiguous-k (global).
template <int NB, int KS>
__device__ __forceinline__ void gemm3xN(const __bf16* A, int lda, const __bf16* const (&B)[NB],
                                        int c16, int quad, f32x4 (&acc)[NB][3]) {
#pragma unroll
  for (int i = 0; i < NB; ++i) {
    acc[i][0] = f32x4{0,0,0,0}; acc[i][1] = f32x4{0,0,0,0}; acc[i][2] = f32x4{0,0,0,0};
  }
#pragma unroll
  for (int ks = 0; ks < KS; ++ks) {
    int ko = ks * 32 + quad * 8;
    bf16x8 a0 = ld8(A + c16 * lda + ko);
    bf16x8 a1 = ld8(A + (16 + c16) * lda + ko);
    bf16x8 a2 = ld8(A + (32 + c16) * lda + ko);
#pragma unroll
    for (int i = 0; i < NB; ++i) {
      bf16x8 b = ld8(B[i] + ko);
      acc[i][0] = MFMA(a0, b, acc[i][0]);
      acc[i][1] = MFMA(a1, b, acc[i][1]);
      acc[i][2] = MFMA(a2, b, acc[i][2]);
    }
  }
}

// LayerNorm update; res in C-layout (cols (2w+nt)*16+c16); rewrites res + xbf. 3 barriers.
__device__ __forceinline__ void ln_update(float (&res)[3][2][4], const float* __restrict__ g,
                                          const float* __restrict__ bb, __bf16* xbf, float* part,
                                          float* statsA, float* statsB, int tid, int w, int c16,
                                          int quad) {
#pragma unroll
  for (int mt = 0; mt < 3; ++mt)
#pragma unroll
    for (int r = 0; r < 4; ++r) {
      float s = res[mt][0][r] + res[mt][1][r];
      float ss = res[mt][0][r] * res[mt][0][r] + res[mt][1][r] * res[mt][1][r];
      s += __shfl_xor(s, 1); ss += __shfl_xor(ss, 1);
      s += __shfl_xor(s, 2); ss += __shfl_xor(ss, 2);
      s += __shfl_xor(s, 4); ss += __shfl_xor(ss, 4);
      s += __shfl_xor(s, 8); ss += __shfl_xor(ss, 8);
      if (c16 == 0) {
        int row = mt * 16 + quad * 4 + r;
        part[(w * 48 + row) * 2] = s; part[(w * 48 + row) * 2 + 1] = ss;
      }
    }
  __syncthreads();
  if (tid < 48) {
    float S = 0.f, SS = 0.f;
#pragma unroll
    for (int w2 = 0; w2 < 4; ++w2) { S += part[(w2 * 48 + tid) * 2]; SS += part[(w2 * 48 + tid) * 2 + 1]; }
    float mu = S * 0.0078125f;
    float var = fmaxf(SS * 0.0078125f - mu * mu, 0.f);
    statsA[tid] = mu; statsB[tid] = rsqrtf(var + 1e-5f);
  }
  __syncthreads();
  float gg[2], bv[2];
#pragma unroll
  for (int nt = 0; nt < 2; ++nt) { int col = (2 * w + nt) * 16 + c16; gg[nt] = g[col]; bv[nt] = bb[col]; }
#pragma unroll
  for (int mt = 0; mt < 3; ++mt)
#pragma unroll
    for (int r = 0; r < 4; ++r) {
      int row = mt * 16 + quad * 4 + r;
      float mu = statsA[row], rs = statsB[row];
#pragma unroll
      for (int nt = 0; nt < 2; ++nt) {
        float v = (res[mt][nt][r] - mu) * rs * gg[nt] + bv[nt];
        res[mt][nt][r] = v;
        xbf[row * 136 + (2 * w + nt) * 16 + c16] = (__bf16)(row < NN_ ? v : 0.f);
      }
    }
  __syncthreads();
}

// ---------------- per-tree fused encoder: wave-private attention ----------------
__global__ __launch_bounds__(256, 3) void tree_enc(
    const float* __restrict__ forest, const int* __restrict__ adjacency,
    const int* __restrict__ node_order, const float* __restrict__ b_in,
    const float* __restrict__ qkv_b, const float* __restrict__ ao_b,
    const float* __restrict__ ff1_b, const float* __restrict__ ff2_b,
    const float* __restrict__ ln1_g, const float* __restrict__ ln1_b,
    const float* __restrict__ ln2_g, const float* __restrict__ ln2_b,
    const __bf16* __restrict__ wb, __bf16* __restrict__ Xg) {
  const int f = blockIdx.x, tid = threadIdx.x;
  const int lane = tid & 63, w = tid >> 6, c16 = lane & 15, quad = lane >> 4;

  __shared__ alignas(16) unsigned char smem[SM_SZ];
  __bf16* qk     = (__bf16*)(smem + w * 6912);  // per-wave [48][72]: q cols 0..31, k cols 32..63
  __bf16* fbf    = (__bf16*)smem;               // [48][40] (init only)
  __bf16* hbf    = (__bf16*)smem;               // [48][264] (FF only)
  int*    bits_s = (int*)(smem + 3840);         // [48][4] pos bitmask (init/embed only)
  int*    adj_s  = (int*)(smem + 4608);
  int*    depth_s= (int*)(smem + 5104);
  float*  part   = (float*)(smem + 25344);      // ln_update only (qk tail dead then)
  float*  statsA = (float*)(smem + 26880);
  float*  statsB = (float*)(smem + 27072);
  __bf16* xbf    = (__bf16*)(smem + 27648);     // [48][136] x / attn-o (aliased)

  // ---- init phase 1: zeros (fbf + bits), adjacency, depths ----
  for (int i = tid; i < 1152; i += 256) ((int*)smem)[i] = 0;  // fbf [0,3840) + bits [3840,4608)
  if (tid < E_ * 3) adj_s[tid] = adjacency[f * (E_ * 3) + tid];
  if (w == 1) {
    int v = (lane < NN_) ? node_order[f * NN_ + lane] : 0;
    int mx = v;
#pragma unroll
    for (int m = 1; m < 64; m <<= 1) mx = max(mx, __shfl_xor(mx, m));
    if (lane < 48) depth_s[lane] = (lane < NN_) ? (mx - v) : 0;
  }
  __syncthreads();

  // ---- init phase 2: stage forest bf16 + positional walk (bitmask, by depth level) ----
  for (int i = tid; i < NN_ * 32; i += 256) {
    int r = i >> 5, c = i & 31;
    fbf[r * 40 + c] = (__bf16)forest[f * (NN_ * 32) + i];
  }
  if (w == 0) {
    // one edge per lane; process levels in parallel. pos values are 0/1 at distinct
    // indices (distinct ancestor depths) => 128-bit OR mask per node == the sum.
    int pl = -1, cl = 0, pd = 0, idx = 0;
    if (lane < E_) {
      int p = adj_s[lane * 3], c = adj_s[lane * 3 + 1], s = adj_s[lane * 3 + 2];
      if (p >= 0 && c >= 0) {
        pl = p - f * NN_; cl = c - f * NN_;
        int si = s + 1; si = si < 0 ? 0 : (si > 2 ? 2 : si);
        pd = depth_s[pl]; idx = pd * 3 + si;
      }
    }
    int dv = (lane < NN_) ? depth_s[lane] : 0;
#pragma unroll
    for (int m = 1; m < 64; m <<= 1) dv = max(dv, __shfl_xor(dv, m));
    int plc = pl < 0 ? 0 : pl;
    int bm = 1 << (idx & 31), wi = idx >> 5;
    int m0 = (wi == 0) ? bm : 0, m1 = (wi == 1) ? bm : 0;
    int m2 = (wi == 2) ? bm : 0, m3 = (wi == 3) ? bm : 0;
    for (int d = 0; d < dv; ++d) {
      int4 pb = *(int4*)&bits_s[plc * 4];
      if (pl >= 0 && pd == d) {
        int4 nb;
        nb.x = pb.x | m0; nb.y = pb.y | m1; nb.z = pb.z | m2; nb.w = pb.w | m3;
        *(int4*)&bits_s[cl * 4] = nb;
      }
      asm volatile("s_waitcnt lgkmcnt(0)" ::: "memory");
    }
  }
  __syncthreads();

  // ---- embed: x0 = forest @ W_in^T + b_in + pos ----
  float res[3][2][4];
  {
    const __bf16* Bw[2] = { wb + WB_WIN + ((2 * w) * 16 + c16) * 32,
                            wb + WB_WIN + ((2 * w + 1) * 16 + c16) * 32 };
    f32x4 ea[2][3];
    gemm3xN<2, 1>(fbf, 40, Bw, c16, quad, ea);
#pragma unroll
    for (int nt = 0; nt < 2; ++nt) {
      int col = (2 * w + nt) * 16 + c16;
      float bi = b_in[col];
      int wsel = col >> 5, shv = col & 31;
#pragma unroll
      for (int mt = 0; mt < 3; ++mt)
#pragma unroll
        for (int r = 0; r < 4; ++r) {
          int row = mt * 16 + quad * 4 + r;
          float v = ea[nt][mt][r] + bi + (float)((bits_s[row * 4 + wsel] >> shv) & 1);
          res[mt][nt][r] = v;
          xbf[row * 136 + col] = (__bf16)(row < NN_ ? v : 0.f);
        }
    }
  }
  __syncthreads();

  // ---- encoder layers ----
  for (int l = 0; l < 2; ++l) {
    // === per-wave qkv GEMM, head h = w; three 2-tile passes (Q, K, V; peak acc 24) ===
    int vp[2][3][2];  // [s = d-half][node m-tile][node pair]: V[mt*16+quad*4+2h..+1][s*16+c16]
    {
      const __bf16* qkvW = wb + WB_QKV + l * 384 * 128;
      const float* qbl = qkv_b + l * 384;
#pragma unroll
      for (int p = 0; p < 3; ++p) {  // 0=Q, 1=K, 2=V
        f32x4 qa[2][3];
#pragma unroll
        for (int j = 0; j < 2; ++j) { qa[j][0] = f32x4{0,0,0,0}; qa[j][1] = f32x4{0,0,0,0}; qa[j][2] = f32x4{0,0,0,0}; }
        const __bf16* Bp[2];
#pragma unroll
        for (int j = 0; j < 2; ++j)
          Bp[j] = qkvW + (p * 128 + w * 32 + j * 16 + c16) * 128;
#pragma unroll
        for (int ks = 0; ks < 4; ++ks) {
          int ko = ks * 32 + quad * 8;
          bf16x8 a0 = ld8(xbf + c16 * 136 + ko);
          bf16x8 a1 = ld8(xbf + (16 + c16) * 136 + ko);
          bf16x8 a2 = ld8(xbf + (32 + c16) * 136 + ko);
#pragma unroll
          for (int j = 0; j < 2; ++j) {
            bf16x8 b = ld8(Bp[j] + ko);
            qa[j][0] = MFMA(a0, b, qa[j][0]);
            qa[j][1] = MFMA(a1, b, qa[j][1]);
            qa[j][2] = MFMA(a2, b, qa[j][2]);
          }
        }
#pragma unroll
        for (int j = 0; j < 2; ++j) {
          float bias = qbl[p * 128 + w * 32 + j * 16 + c16];
#pragma unroll
          for (int mt = 0; mt < 3; ++mt) {
            if (p == 2) {  // V -> registers (bf16 pair-packed), no LDS round-trip
              vp[j][mt][0] = pack2(qa[j][mt][0] + bias, qa[j][mt][1] + bias);
              vp[j][mt][1] = pack2(qa[j][mt][2] + bias, qa[j][mt][3] + bias);
            } else {       // Q (scaled) / K -> qk[node][col] (wave-private LDS)
              int colo = (p == 0 ? 0 : 32) + j * 16 + c16;
#pragma unroll
              for (int r = 0; r < 4; ++r) {
                float v = qa[j][mt][r] + bias;
                if (p == 0) v *= SCALE_;
                qk[(mt * 16 + quad * 4 + r) * 72 + colo] = (__bf16)v;
              }
            }
          }
        }
      }
    }
    // NO barrier here (slid down): scores/softmax/PV touch only wave-private qk +
    // registers. The xbf-read vs obf-write hazard is guarded by the barrier
    // immediately before the obf write below.

    // === scores S^T = K Q^T, 9 tiles in-register ===
    f32x4 st[3][3];
    {
      bf16x8 ka[3], qb2[3];
#pragma unroll
      for (int m = 0; m < 3; ++m) ka[m] = ld8(qk + (m * 16 + c16) * 72 + 32 + quad * 8);
#pragma unroll
      for (int n = 0; n < 3; ++n) qb2[n] = ld8(qk + (n * 16 + c16) * 72 + quad * 8);
#pragma unroll
      for (int m = 0; m < 3; ++m)
#pragma unroll
        for (int n = 0; n < 3; ++n) {
          f32x4 z{0,0,0,0};
          st[m][n] = MFMA(ka[m], qb2[n], z);
        }
    }

    // === softmax fully in-register (query = n-tile*16 + c16; keys on quad/reg) ===
    int dwp[3][3][2];  // packed P bf16 pairs [key-tile][query-tile][dword]
#pragma unroll
    for (int n = 0; n < 3; ++n) {
      float mx = -3.0e38f;
#pragma unroll
      for (int m = 0; m < 3; ++m)
#pragma unroll
        for (int r = 0; r < 4; ++r) {
          bool valid = (m < 2) || (quad * 4 + r < 10);  // key < 42
          mx = fmaxf(mx, valid ? st[m][n][r] : -3.0e38f);
        }
      mx = fmaxf(mx, __shfl_xor(mx, 16));
      mx = fmaxf(mx, __shfl_xor(mx, 32));
      float sm = 0.f, ev[3][4];
#pragma unroll
      for (int m = 0; m < 3; ++m)
#pragma unroll
        for (int r = 0; r < 4; ++r) {
          bool valid = (m < 2) || (quad * 4 + r < 10);
          float e = valid ? __expf(st[m][n][r] - mx) : 0.f;
          ev[m][r] = e; sm += e;
        }
      sm += __shfl_xor(sm, 16);
      sm += __shfl_xor(sm, 32);
      float inv = 1.f / sm;
#pragma unroll
      for (int m = 0; m < 3; ++m) {
        dwp[m][n][0] = pack2(ev[m][0] * inv, ev[m][1] * inv);
        dwp[m][n][1] = pack2(ev[m][2] * inv, ev[m][3] * inv);
      }
    }

    // === PV: both P and V^T fragments via shuffle-transpose (no LDS round-trip) ===
    f32x4 ov[3][2];
#pragma unroll
    for (int mtq = 0; mtq < 3; ++mtq) { ov[mtq][0] = f32x4{0,0,0,0}; ov[mtq][1] = f32x4{0,0,0,0}; }
    int sl0 = (2 * (quad & 1)) * 16 + c16, sl1 = sl0 + 16;
    bool hi = quad > 1;
#pragma unroll
    for (int ks = 0; ks < 2; ++ks) {
      // B-operand: V[g..g+7][d=nt*16+c16], g = koB(quad). dword m holds nodes (g+2m, g+2m+1):
      //   src lane = (((quad<<1)+(m>>1))&3)*16 + c16, reg = vp[nt][mt_src][m&1],
      //   mt_src = quad>>1 (ks=0) | 2 (ks=1).  Matches A-operand koB exactly (A=0 there).
      bf16x8 bv[2];
#pragma unroll
      for (int nt = 0; nt < 2; ++nt) {
        union { int i[4]; bf16x8 v; } U;
#pragma unroll
        for (int m = 0; m < 4; ++m) {
          int srcl = (((quad << 1) + (m >> 1)) & 3) * 16 + c16;
          if (ks == 0) {
            int x0 = __shfl(vp[nt][0][m & 1], srcl);
            int x1 = __shfl(vp[nt][1][m & 1], srcl);
            U.i[m] = (quad >> 1) ? x1 : x0;
          } else {
            U.i[m] = __shfl(vp[nt][2][m & 1], srcl);
          }
        }
        bv[nt] = U.v;
      }
      int lo = 2 * ks;
#pragma unroll
      for (int mtq = 0; mtq < 3; ++mtq) {
        int a0 = __shfl(dwp[lo][mtq][0], sl0), a1 = __shfl(dwp[lo][mtq][1], sl0);
        int a2 = __shfl(dwp[lo][mtq][0], sl1), a3 = __shfl(dwp[lo][mtq][1], sl1);
        int b0 = 0, b1 = 0, b2 = 0, b3 = 0;
        if (ks == 0) {
          b0 = __shfl(dwp[1][mtq][0], sl0); b1 = __shfl(dwp[1][mtq][1], sl0);
          b2 = __shfl(dwp[1][mtq][0], sl1); b3 = __shfl(dwp[1][mtq][1], sl1);
        }
        union { int i[4]; bf16x8 v; } A;
        A.i[0] = hi ? b0 : a0; A.i[1] = hi ? b1 : a1;
        A.i[2] = hi ? b2 : a2; A.i[3] = hi ? b3 : a3;
        ov[mtq][0] = MFMA(A.v, bv[0], ov[mtq][0]);
        ov[mtq][1] = MFMA(A.v, bv[1], ov[mtq][1]);
      }
    }
    __syncthreads();  // slid barrier: all waves done reading xbf (qkv) before overwrite
    // obf (= xbf alias) write: head slab cols w*32..w*32+31
#pragma unroll
    for (int mtq = 0; mtq < 3; ++mtq)
#pragma unroll
      for (int nt = 0; nt < 2; ++nt)
#pragma unroll
        for (int r = 0; r < 4; ++r) {
          int row = mtq * 16 + quad * 4 + r;
          xbf[row * 136 + w * 32 + nt * 16 + c16] = (__bf16)(row < NN_ ? ov[mtq][nt][r] : 0.f);
        }
    __syncthreads();

    // === attn-out + residual ===
    {
      const __bf16* aoW = wb + WB_AO + l * 128 * 128;
      const __bf16* Bs[2] = { aoW + ((2 * w) * 16 + c16) * 128, aoW + ((2 * w + 1) * 16 + c16) * 128 };
      f32x4 aa[2][3];
      gemm3xN<2, 4>(xbf, 136, Bs, c16, quad, aa);
#pragma unroll
      for (int nt = 0; nt < 2; ++nt) {
        float ab = ao_b[l * 128 + (2 * w + nt) * 16 + c16];
#pragma unroll
        for (int mt = 0; mt < 3; ++mt)
#pragma unroll
          for (int r = 0; r < 4; ++r) res[mt][nt][r] += aa[nt][mt][r] + ab;
      }
    }
    ln_update(res, ln1_g + l * 128, ln1_b + l * 128, xbf, part, statsA, statsB, tid, w, c16, quad);

    // === FF1 -> hbf (relu, bf16); two 2-tile passes (peak acc 24) ===
    {
      const __bf16* f1W = wb + WB_FF1 + l * 256 * 128;
#pragma unroll
      for (int pass = 0; pass < 2; ++pass) {
        const __bf16* Bs[2] = { f1W + ((4 * w + 2 * pass) * 16 + c16) * 128,
                                f1W + ((4 * w + 2 * pass + 1) * 16 + c16) * 128 };
        f32x4 fa[2][3];
        gemm3xN<2, 4>(xbf, 136, Bs, c16, quad, fa);
#pragma unroll
        for (int j = 0; j < 2; ++j) {
          int nt = 2 * pass + j;
          int col = (4 * w + nt) * 16 + c16;
          float b1 = ff1_b[l * 256 + col];
#pragma unroll
          for (int mt = 0; mt < 3; ++mt)
#pragma unroll
            for (int r = 0; r < 4; ++r) {
              int row = mt * 16 + quad * 4 + r;
              float v = fmaxf(fa[j][mt][r] + b1, 0.f);
              hbf[row * 264 + col] = (__bf16)(row < NN_ ? v : 0.f);
            }
        }
      }
    }
    __syncthreads();

    // === FF2 + residual ===
    {
      const __bf16* f2W = wb + WB_FF2 + l * 128 * 256;
      const __bf16* Bs[2] = { f2W + ((2 * w) * 16 + c16) * 256, f2W + ((2 * w + 1) * 16 + c16) * 256 };
      f32x4 fa[2][3];
      gemm3xN<2, 8>(hbf, 264, Bs, c16, quad, fa);
#pragma unroll
      for (int nt = 0; nt < 2; ++nt) {
        float fb2 = ff2_b[l * 128 + (2 * w + nt) * 16 + c16];
#pragma unroll
        for (int mt = 0; mt < 3; ++mt)
#pragma unroll
          for (int r = 0; r < 4; ++r) res[mt][nt][r] += fa[nt][mt][r] + fb2;
      }
    }
    ln_update(res, ln2_g + l * 128, ln2_b + l * 128, xbf, part, statsA, statsB, tid, w, c16, quad);
  }

  // ---- stage out: x_final (bf16) -> ws X[f][5376] ----
  {
    __bf16* Xf = Xg + (size_t)f * 5376;
    for (int c = tid; c < 672; c += 256) {
      int row = c >> 4, co = (c & 15) * 8;
      *(bf16x8*)(Xf + row * 128 + co) = ld8(xbf + row * 136 + co);
    }
  }
}

// ---------------- output projection + final LN, K split 4-way, 6-deep pipeline ----------------
__global__ __launch_bounds__(1024) void wout_k(const __bf16* __restrict__ X,
                                               const __bf16* __restrict__ Wb,
                                               const float* __restrict__ b_out,
                                               const float* __restrict__ lnf_g,
                                               const float* __restrict__ lnf_b,
                                               float* __restrict__ out) {
  const int blk = blockIdx.x, tid = threadIdx.x;
  const int lane = tid & 63, w2 = tid >> 6, wc = w2 & 3, kh = w2 >> 2;  // wc 0..3, kh 0..3
  const int c16 = lane & 15, quad = lane >> 4;
  __shared__ float cout[64 * 132];
  f32x4 acc0{0,0,0,0}, acc1{0,0,0,0};
  const __bf16* Ar = X + (size_t)(blk * 16 + c16) * 5376 + kh * 1344;
  const __bf16* B0 = Wb + (size_t)((2 * wc) * 16 + c16) * 5376 + kh * 1344;
  const __bf16* B1 = Wb + (size_t)((2 * wc + 1) * 16 + c16) * 5376 + kh * 1344;
  // 6-deep software pipeline: ~6x48B in flight per wave (16 waves/CU) to cover HBM
  // latency on the A stream. Fully unrolled -> all buffer indices compile-time (regs).
  bf16x8 ab[6], b0b[6], b1b[6];
#pragma unroll
  for (int d = 0; d < 6; ++d) {
    int ko = d * 32 + quad * 8;
    ab[d] = ld8(Ar + ko); b0b[d] = ld8(B0 + ko); b1b[d] = ld8(B1 + ko);
  }
#pragma unroll
  for (int ks = 0; ks < 42; ++ks) {
    const int cur = ks % 6;
    acc0 = MFMA(ab[cur], b0b[cur], acc0);
    acc1 = MFMA(ab[cur], b1b[cur], acc1);
    if (ks + 6 < 42) {
      int ko = (ks + 6) * 32 + quad * 8;
      ab[cur] = ld8(Ar + ko); b0b[cur] = ld8(B0 + ko); b1b[cur] = ld8(B1 + ko);
    }
  }
#pragma unroll
  for (int nt = 0; nt < 2; ++nt) {
    f32x4 av = nt ? acc1 : acc0;
#pragma unroll
    for (int r = 0; r < 4; ++r) cout[(kh * 16 + quad * 4 + r) * 132 + (2 * wc + nt) * 16 + c16] = av[r];
  }
  __syncthreads();
  if (w2 < 4) {
#pragma unroll
    for (int rr = 0; rr < 4; ++rr) {
      int row = w2 * 4 + rr;
      float v0 = cout[row * 132 + lane] + cout[(16 + row) * 132 + lane] +
                 cout[(32 + row) * 132 + lane] + cout[(48 + row) * 132 + lane] + b_out[lane];
      float v1 = cout[row * 132 + 64 + lane] + cout[(16 + row) * 132 + 64 + lane] +
                 cout[(32 + row) * 132 + 64 + lane] + cout[(48 + row) * 132 + 64 + lane] + b_out[64 + lane];
      float s = v0 + v1, ss = v0 * v0 + v1 * v1;
#pragma unroll
      for (int m = 1; m < 64; m <<= 1) { s += __shfl_xor(s, m); ss += __shfl_xor(ss, m); }
      float mu = s * 0.0078125f;
      float var = fmaxf(ss * 0.0078125f - mu * mu, 0.f);
      float rs = rsqrtf(var + 1e-5f);
      size_t o = (size_t)(blk * 16 + row) * 128;
      out[o + lane] = (v0 - mu) * rs * lnf_g[lane] + lnf_b[lane];
      out[o + 64 + lane] = (v1 - mu) * rs * lnf_g[64 + lane] + lnf_b[64 + lane];
    }
  }
}

extern "C" void kernel_launch(void* const* d_in, const int* in_sizes, int n_in,
                              void* d_out, int out_size, void* d_ws, size_t ws_size,
                              hipStream_t stream) {
  const float* forest     = (const float*)d_in[0];
  const int*   adjacency  = (const int*)d_in[1];
  const int*   node_order = (const int*)d_in[2];
  const float* W_in       = (const float*)d_in[3];
  const float* b_in       = (const float*)d_in[4];
  const float* qkv_b      = (const float*)d_in[6];
  const float* ao_b       = (const float*)d_in[8];
  const float* ff1_b      = (const float*)d_in[10];
  const float* ff2_b      = (const float*)d_in[12];
  const float* ln1_g      = (const float*)d_in[13];
  const float* ln1_b      = (const float*)d_in[14];
  const float* ln2_g      = (const float*)d_in[15];
  const float* ln2_b      = (const float*)d_in[16];
  const float* b_out      = (const float*)d_in[18];
  const float* lnf_g      = (const float*)d_in[19];
  const float* lnf_b      = (const float*)d_in[20];
  __bf16* wb = (__bf16*)d_ws;
  float* out = (float*)d_out;

  prep_bf16<<<dim3(PREP_N / 256), dim3(256), 0, stream>>>(
      W_in, (const float*)d_in[5], (const float*)d_in[7], (const float*)d_in[9],
      (const float*)d_in[11], (const float*)d_in[17], wb);
  tree_enc<<<dim3(FB_), dim3(256), 0, stream>>>(forest, adjacency, node_order, b_in, qkv_b, ao_b,
                                                ff1_b, ff2_b, ln1_g, ln1_b, ln2_g, ln2_b, wb,
                                                wb + WB_X);
  wout_k<<<dim3(FB_ / 16), dim3(1024), 0, stream>>>(wb + WB_X, wb + WB_WOUT, b_out, lnf_g, lnf_b,
                                                    out);
}

// Round 13
// 462.629 us; speedup vs baseline: 1.0982x; 1.0286x over previous
//
#include <hip/hip_runtime.h>
#include <hip/hip_bf16.h>

typedef __bf16 bf16x8 __attribute__((ext_vector_type(8)));
typedef float  f32x4  __attribute__((ext_vector_type(4)));

#define MFMA(a,b,c) __builtin_amdgcn_mfma_f32_16x16x32_bf16((a),(b),(c),0,0,0)

// problem constants
#define NN_  42
#define E_   41
#define FB_  4096
#define SCALE_ 0.17677669529663687f  // 1/sqrt(32)

// ws layout, element offsets into __bf16* ws (layouts preserved == MFMA B-operand layout)
#define WB_WIN  0         // [128][32]
#define WB_QKV  4096      // [L][384][128]
#define WB_AO   102400    // [L][128][128]
#define WB_FF1  135168    // [L][256][128]
#define WB_FF2  200704    // [L][128][256]
#define WB_WOUT 266240    // [128][5376]
#define WB_X    954368    // [4096][5376] staged x_final (bf16)
#define PREP_N  954368

// === TWO TREES PER BLOCK (M=96) ===  r12 post-mortem: per-wave MFMA+VALU ~14% of
// serial time -> doubling work/wave at constant overhead is cheap. 2 trees stacked
// (rows 0-47 tree0, 48-95 tree1; 48=3x16 so row-tiles align). LDS 81408 -> 2 blocks/CU
// (81920x2=163840), 8 waves/CU at 2/SIMD -> 256-reg budget (kills the r5/r6/r9/r10
// spill ceiling). Rounds: 4096/768=5.33 -> 2048/512=4.0. B-weights amortize over 6
// row-tiles. Spill gate: WRITE_SIZE==43008 exactly, else revert to r12.
// smem (bytes), total 81408:
//  [0,55296)      per-wave qk[96][72] (q cols 0..31, k 32..63), w*13824
//                 aliases (lifetime-disjoint):
//                   fbf [96][40]          @0      (init/embed)
//                   bits int[96][4]       @7680   (init/embed; pos bitmask)
//                   adj int[246]          @9216   (init; 2 trees contiguous)
//                   depth int[96]         @10200  (init)
//                   hbf [96][264]         @0      (FF only; 50688 B)
//                   part float[4][96][2]  @50688  (ln only; post-obf qk dead)
//                   statsA/B float[96]    @53760/54144
//  [55296,81408)  xbf/obf [96][136] bf16 (aliased; pre-obf barrier guards swap)
// Strides 72/136/264 hw kept (dword stride ==4 mod 32 -> 2-way free; r4 verified
// stride class immaterial beyond this).
#define SM_SZ 81408

// ---------------- weight cast to bf16 ----------------
__global__ void prep_bf16(const float* __restrict__ W_in, const float* __restrict__ qkv_w,
                          const float* __restrict__ ao_w, const float* __restrict__ ff1_w,
                          const float* __restrict__ ff2_w, const float* __restrict__ W_out,
                          __bf16* __restrict__ wb) {
  int i = blockIdx.x * 256 + threadIdx.x;
  float v;
  if      (i < 4096)   v = W_in[i];
  else if (i < 102400) v = qkv_w[i - 4096];
  else if (i < 135168) v = ao_w[i - 102400];
  else if (i < 200704) v = ff1_w[i - 135168];
  else if (i < 266240) v = ff2_w[i - 200704];
  else if (i < 954368) v = W_out[i - 266240];
  else return;
  wb[i] = (__bf16)v;
}

__device__ __forceinline__ bf16x8 ld8(const __bf16* p) { return *(const bf16x8*)p; }

__device__ __forceinline__ int pack2(float a, float b) {
  union { __bf16 h[2]; int i; } u;
  u.h[0] = (__bf16)a; u.h[1] = (__bf16)b;
  return u.i;
}

// C = A[96xK] * B^T for NB column-tiles; A in LDS (lda halfwords), 6 row-tiles at rt*16.
template <int NB, int KS>
__device__ __forceinline__ void gemm6xN(const __bf16* A, int lda, const __bf16* const (&B)[NB],
                                        int c16, int quad, f32x4 (&acc)[NB][6]) {
#pragma unroll
  for (int i = 0; i < NB; ++i)
#pragma unroll
    for (int rt = 0; rt < 6; ++rt) acc[i][rt] = f32x4{0,0,0,0};
#pragma unroll
  for (int ks = 0; ks < KS; ++ks) {
    int ko = ks * 32 + quad * 8;
    bf16x8 a[6];
#pragma unroll
    for (int rt = 0; rt < 6; ++rt) a[rt] = ld8(A + (rt * 16 + c16) * lda + ko);
#pragma unroll
    for (int i = 0; i < NB; ++i) {
      bf16x8 b = ld8(B[i] + ko);
#pragma unroll
      for (int rt = 0; rt < 6; ++rt) acc[i][rt] = MFMA(a[rt], b, acc[i][rt]);
    }
  }
}

// LayerNorm over 96 rows (2 trees); res[6][2][4] in C-layout; rewrites res + xbf. 3 barriers.
__device__ __forceinline__ void ln_update(float (&res)[6][2][4], const float* __restrict__ g,
                                          const float* __restrict__ bb, __bf16* xbf, float* part,
                                          float* statsA, float* statsB, int tid, int w, int c16,
                                          int quad) {
#pragma unroll
  for (int mt6 = 0; mt6 < 6; ++mt6)
#pragma unroll
    for (int r = 0; r < 4; ++r) {
      float s = res[mt6][0][r] + res[mt6][1][r];
      float ss = res[mt6][0][r] * res[mt6][0][r] + res[mt6][1][r] * res[mt6][1][r];
      s += __shfl_xor(s, 1); ss += __shfl_xor(ss, 1);
      s += __shfl_xor(s, 2); ss += __shfl_xor(ss, 2);
      s += __shfl_xor(s, 4); ss += __shfl_xor(ss, 4);
      s += __shfl_xor(s, 8); ss += __shfl_xor(ss, 8);
      if (c16 == 0) {
        int row = mt6 * 16 + quad * 4 + r;
        part[(w * 96 + row) * 2] = s; part[(w * 96 + row) * 2 + 1] = ss;
      }
    }
  __syncthreads();
  if (tid < 96) {
    float S = 0.f, SS = 0.f;
#pragma unroll
    for (int w2 = 0; w2 < 4; ++w2) { S += part[(w2 * 96 + tid) * 2]; SS += part[(w2 * 96 + tid) * 2 + 1]; }
    float mu = S * 0.0078125f;
    float var = fmaxf(SS * 0.0078125f - mu * mu, 0.f);
    statsA[tid] = mu; statsB[tid] = rsqrtf(var + 1e-5f);
  }
  __syncthreads();
  float gg[2], bv[2];
#pragma unroll
  for (int nt = 0; nt < 2; ++nt) { int col = (2 * w + nt) * 16 + c16; gg[nt] = g[col]; bv[nt] = bb[col]; }
#pragma unroll
  for (int t = 0; t < 2; ++t)
#pragma unroll
    for (int mt = 0; mt < 3; ++mt)
#pragma unroll
      for (int r = 0; r < 4; ++r) {
        int mt6 = t * 3 + mt;
        int row = mt6 * 16 + quad * 4 + r;      // = t*48 + mt*16 + quad*4 + r
        int rloc = mt * 16 + quad * 4 + r;
        float mu = statsA[row], rs = statsB[row];
#pragma unroll
        for (int nt = 0; nt < 2; ++nt) {
          float v = (res[mt6][nt][r] - mu) * rs * gg[nt] + bv[nt];
          res[mt6][nt][r] = v;
          xbf[row * 136 + (2 * w + nt) * 16 + c16] = (__bf16)(rloc < NN_ ? v : 0.f);
        }
      }
  __syncthreads();
}

// ---------------- per-block fused encoder: 2 trees, wave-private attention ----------------
__global__ __launch_bounds__(256, 2) void tree_enc(
    const float* __restrict__ forest, const int* __restrict__ adjacency,
    const int* __restrict__ node_order, const float* __restrict__ b_in,
    const float* __restrict__ qkv_b, const float* __restrict__ ao_b,
    const float* __restrict__ ff1_b, const float* __restrict__ ff2_b,
    const float* __restrict__ ln1_g, const float* __restrict__ ln1_b,
    const float* __restrict__ ln2_g, const float* __restrict__ ln2_b,
    const __bf16* __restrict__ wb, __bf16* __restrict__ Xg) {
  const int f0 = blockIdx.x * 2, tid = threadIdx.x;
  const int lane = tid & 63, w = tid >> 6, c16 = lane & 15, quad = lane >> 4;

  __shared__ alignas(16) unsigned char smem[SM_SZ];
  __bf16* qk     = (__bf16*)(smem + w * 13824);  // per-wave [96][72]
  __bf16* fbf    = (__bf16*)smem;                // [96][40] (init only)
  __bf16* hbf    = (__bf16*)smem;                // [96][264] (FF only)
  int*    bits_s = (int*)(smem + 7680);          // [96][4] pos bitmask
  int*    adj_s  = (int*)(smem + 9216);          // [246]
  int*    depth_s= (int*)(smem + 10200);         // [96]
  float*  part   = (float*)(smem + 50688);       // ln only (qk dead then)
  float*  statsA = (float*)(smem + 53760);
  float*  statsB = (float*)(smem + 54144);
  __bf16* xbf    = (__bf16*)(smem + 55296);      // [96][136] x / attn-o (aliased)

  // ---- init phase 1: zeros (fbf + bits), adjacency (both trees), depths ----
  for (int i = tid; i < 2304; i += 256) ((int*)smem)[i] = 0;  // fbf [0,7680) + bits [7680,9216)
  if (tid < 246) adj_s[tid] = adjacency[f0 * (E_ * 3) + tid];
  if (w >= 2) {
    int t = w - 2;
    int v = (lane < NN_) ? node_order[(f0 + t) * NN_ + lane] : 0;
    int mx = v;
#pragma unroll
    for (int m = 1; m < 64; m <<= 1) mx = max(mx, __shfl_xor(mx, m));
    if (lane < 48) depth_s[t * 48 + lane] = (lane < NN_) ? (mx - v) : 0;
  }
  __syncthreads();

  // ---- init phase 2: stage forest bf16 + positional walks (wave t handles tree t) ----
  for (int i = tid; i < 2 * NN_ * 32; i += 256) {
    int tree = i >= 1344 ? 1 : 0;
    int j = i - tree * 1344;
    fbf[(tree * 48 + (j >> 5)) * 40 + (j & 31)] = (__bf16)forest[(f0 + tree) * 1344 + j];
  }
  if (w < 2) {
    const int t = w;
    int pl = -1, cl = 0, pd = 0, idx = 0;
    if (lane < E_) {
      int p = adj_s[t * 123 + lane * 3], c = adj_s[t * 123 + lane * 3 + 1],
          s = adj_s[t * 123 + lane * 3 + 2];
      if (p >= 0 && c >= 0) {
        pl = p - (f0 + t) * NN_; cl = c - (f0 + t) * NN_;
        int si = s + 1; si = si < 0 ? 0 : (si > 2 ? 2 : si);
        pd = depth_s[t * 48 + pl]; idx = pd * 3 + si;
      }
    }
    int dv = (lane < NN_) ? depth_s[t * 48 + lane] : 0;
#pragma unroll
    for (int m = 1; m < 64; m <<= 1) dv = max(dv, __shfl_xor(dv, m));
    int plc = t * 48 + (pl < 0 ? 0 : pl);
    int clr = t * 48 + cl;
    int bm = 1 << (idx & 31), wi = idx >> 5;
    int m0 = (wi == 0) ? bm : 0, m1 = (wi == 1) ? bm : 0;
    int m2 = (wi == 2) ? bm : 0, m3 = (wi == 3) ? bm : 0;
    for (int d = 0; d < dv; ++d) {
      int4 pb = *(int4*)&bits_s[plc * 4];
      if (pl >= 0 && pd == d) {
        int4 nb;
        nb.x = pb.x | m0; nb.y = pb.y | m1; nb.z = pb.z | m2; nb.w = pb.w | m3;
        *(int4*)&bits_s[clr * 4] = nb;
      }
      asm volatile("s_waitcnt lgkmcnt(0)" ::: "memory");
    }
  }
  __syncthreads();

  // ---- embed: x0 = forest @ W_in^T + b_in + pos ----
  float res[6][2][4];
  {
    const __bf16* Bw[2] = { wb + WB_WIN + ((2 * w) * 16 + c16) * 32,
                            wb + WB_WIN + ((2 * w + 1) * 16 + c16) * 32 };
    f32x4 ea[2][6];
    gemm6xN<2, 1>(fbf, 40, Bw, c16, quad, ea);
#pragma unroll
    for (int nt = 0; nt < 2; ++nt) {
      int col = (2 * w + nt) * 16 + c16;
      float bi = b_in[col];
      int wsel = col >> 5, shv = col & 31;
#pragma unroll
      for (int t = 0; t < 2; ++t)
#pragma unroll
        for (int mt = 0; mt < 3; ++mt)
#pragma unroll
          for (int r = 0; r < 4; ++r) {
            int mt6 = t * 3 + mt;
            int row = mt6 * 16 + quad * 4 + r;
            int rloc = mt * 16 + quad * 4 + r;
            float v = ea[nt][mt6][r] + bi + (float)((bits_s[row * 4 + wsel] >> shv) & 1);
            res[mt6][nt][r] = v;
            xbf[row * 136 + col] = (__bf16)(rloc < NN_ ? v : 0.f);
          }
    }
  }
  __syncthreads();

  // ---- encoder layers ----
  for (int l = 0; l < 2; ++l) {
    // === per-wave qkv GEMM, head h = w, both trees; three 2-tile passes ===
    int vp[2][6][2];  // [d-half][tree*3+mtile][node pair]
    {
      const __bf16* qkvW = wb + WB_QKV + l * 384 * 128;
      const float* qbl = qkv_b + l * 384;
#pragma unroll
      for (int p = 0; p < 3; ++p) {  // 0=Q, 1=K, 2=V
        f32x4 qa[2][6];
        const __bf16* Bp[2];
#pragma unroll
        for (int j = 0; j < 2; ++j)
          Bp[j] = qkvW + (p * 128 + w * 32 + j * 16 + c16) * 128;
        gemm6xN<2, 4>(xbf, 136, Bp, c16, quad, qa);
#pragma unroll
        for (int j = 0; j < 2; ++j) {
          float bias = qbl[p * 128 + w * 32 + j * 16 + c16];
#pragma unroll
          for (int mt6 = 0; mt6 < 6; ++mt6) {
            if (p == 2) {  // V -> registers
              vp[j][mt6][0] = pack2(qa[j][mt6][0] + bias, qa[j][mt6][1] + bias);
              vp[j][mt6][1] = pack2(qa[j][mt6][2] + bias, qa[j][mt6][3] + bias);
            } else {       // Q (scaled) / K -> qk[row][col] (wave-private LDS)
              int colo = (p == 0 ? 0 : 32) + j * 16 + c16;
#pragma unroll
              for (int r = 0; r < 4; ++r) {
                float v = qa[j][mt6][r] + bias;
                if (p == 0) v *= SCALE_;
                qk[(mt6 * 16 + quad * 4 + r) * 72 + colo] = (__bf16)v;
              }
            }
          }
        }
      }
    }
    // NO barrier: attention math is wave-private (qk slab + regs).

    f32x4 ovv[2][3][2];
#pragma unroll
    for (int t = 0; t < 2; ++t) {
      // === scores S^T = K Q^T (tree t) ===
      f32x4 st[3][3];
      {
        bf16x8 ka[3], qb2[3];
#pragma unroll
        for (int m = 0; m < 3; ++m) ka[m] = ld8(qk + (t * 48 + m * 16 + c16) * 72 + 32 + quad * 8);
#pragma unroll
        for (int n = 0; n < 3; ++n) qb2[n] = ld8(qk + (t * 48 + n * 16 + c16) * 72 + quad * 8);
#pragma unroll
        for (int m = 0; m < 3; ++m)
#pragma unroll
          for (int n = 0; n < 3; ++n) {
            f32x4 z{0,0,0,0};
            st[m][n] = MFMA(ka[m], qb2[n], z);
          }
      }

      // === softmax fully in-register ===
      int dwp[3][3][2];
#pragma unroll
      for (int n = 0; n < 3; ++n) {
        float mx = -3.0e38f;
#pragma unroll
        for (int m = 0; m < 3; ++m)
#pragma unroll
          for (int r = 0; r < 4; ++r) {
            bool valid = (m < 2) || (quad * 4 + r < 10);  // key < 42
            mx = fmaxf(mx, valid ? st[m][n][r] : -3.0e38f);
          }
        mx = fmaxf(mx, __shfl_xor(mx, 16));
        mx = fmaxf(mx, __shfl_xor(mx, 32));
        float sm = 0.f, ev[3][4];
#pragma unroll
        for (int m = 0; m < 3; ++m)
#pragma unroll
          for (int r = 0; r < 4; ++r) {
            bool valid = (m < 2) || (quad * 4 + r < 10);
            float e = valid ? __expf(st[m][n][r] - mx) : 0.f;
            ev[m][r] = e; sm += e;
          }
        sm += __shfl_xor(sm, 16);
        sm += __shfl_xor(sm, 32);
        float inv = 1.f / sm;
#pragma unroll
        for (int m = 0; m < 3; ++m) {
          dwp[m][n][0] = pack2(ev[m][0] * inv, ev[m][1] * inv);
          dwp[m][n][1] = pack2(ev[m][2] * inv, ev[m][3] * inv);
        }
      }

      // === PV: P and V^T fragments via shuffle-transpose ===
#pragma unroll
      for (int mtq = 0; mtq < 3; ++mtq) { ovv[t][mtq][0] = f32x4{0,0,0,0}; ovv[t][mtq][1] = f32x4{0,0,0,0}; }
      int sl0 = (2 * (quad & 1)) * 16 + c16, sl1 = sl0 + 16;
      bool hi = quad > 1;
#pragma unroll
      for (int ks = 0; ks < 2; ++ks) {
        bf16x8 bv[2];
#pragma unroll
        for (int nt = 0; nt < 2; ++nt) {
          union { int i[4]; bf16x8 v; } U;
#pragma unroll
          for (int m = 0; m < 4; ++m) {
            int srcl = (((quad << 1) + (m >> 1)) & 3) * 16 + c16;
            if (ks == 0) {
              int x0 = __shfl(vp[nt][t * 3 + 0][m & 1], srcl);
              int x1 = __shfl(vp[nt][t * 3 + 1][m & 1], srcl);
              U.i[m] = (quad >> 1) ? x1 : x0;
            } else {
              U.i[m] = __shfl(vp[nt][t * 3 + 2][m & 1], srcl);
            }
          }
          bv[nt] = U.v;
        }
        int lo = 2 * ks;
#pragma unroll
        for (int mtq = 0; mtq < 3; ++mtq) {
          int a0 = __shfl(dwp[lo][mtq][0], sl0), a1 = __shfl(dwp[lo][mtq][1], sl0);
          int a2 = __shfl(dwp[lo][mtq][0], sl1), a3 = __shfl(dwp[lo][mtq][1], sl1);
          int b0 = 0, b1 = 0, b2 = 0, b3 = 0;
          if (ks == 0) {
            b0 = __shfl(dwp[1][mtq][0], sl0); b1 = __shfl(dwp[1][mtq][1], sl0);
            b2 = __shfl(dwp[1][mtq][0], sl1); b3 = __shfl(dwp[1][mtq][1], sl1);
          }
          union { int i[4]; bf16x8 v; } A;
          A.i[0] = hi ? b0 : a0; A.i[1] = hi ? b1 : a1;
          A.i[2] = hi ? b2 : a2; A.i[3] = hi ? b3 : a3;
          ovv[t][mtq][0] = MFMA(A.v, bv[0], ovv[t][mtq][0]);
          ovv[t][mtq][1] = MFMA(A.v, bv[1], ovv[t][mtq][1]);
        }
      }
    }
    __syncthreads();  // all waves done reading xbf (qkv) before overwrite as obf
    // obf (= xbf alias) write: head slab cols w*32..w*32+31, both trees
#pragma unroll
    for (int t = 0; t < 2; ++t)
#pragma unroll
      for (int mtq = 0; mtq < 3; ++mtq)
#pragma unroll
        for (int nt = 0; nt < 2; ++nt)
#pragma unroll
          for (int r = 0; r < 4; ++r) {
            int rloc = mtq * 16 + quad * 4 + r;
            int row = t * 48 + rloc;
            xbf[row * 136 + w * 32 + nt * 16 + c16] = (__bf16)(rloc < NN_ ? ovv[t][mtq][nt][r] : 0.f);
          }
    __syncthreads();

    // === attn-out + residual ===
    {
      const __bf16* aoW = wb + WB_AO + l * 128 * 128;
      const __bf16* Bs[2] = { aoW + ((2 * w) * 16 + c16) * 128, aoW + ((2 * w + 1) * 16 + c16) * 128 };
      f32x4 aa[2][6];
      gemm6xN<2, 4>(xbf, 136, Bs, c16, quad, aa);
#pragma unroll
      for (int nt = 0; nt < 2; ++nt) {
        float ab = ao_b[l * 128 + (2 * w + nt) * 16 + c16];
#pragma unroll
        for (int mt6 = 0; mt6 < 6; ++mt6)
#pragma unroll
          for (int r = 0; r < 4; ++r) res[mt6][nt][r] += aa[nt][mt6][r] + ab;
      }
    }
    ln_update(res, ln1_g + l * 128, ln1_b + l * 128, xbf, part, statsA, statsB, tid, w, c16, quad);

    // === FF1 -> hbf (relu, bf16); two 2-tile passes ===
    {
      const __bf16* f1W = wb + WB_FF1 + l * 256 * 128;
#pragma unroll
      for (int pass = 0; pass < 2; ++pass) {
        const __bf16* Bs[2] = { f1W + ((4 * w + 2 * pass) * 16 + c16) * 128,
                                f1W + ((4 * w + 2 * pass + 1) * 16 + c16) * 128 };
        f32x4 fa[2][6];
        gemm6xN<2, 4>(xbf, 136, Bs, c16, quad, fa);
#pragma unroll
        for (int j = 0; j < 2; ++j) {
          int nt = 2 * pass + j;
          int col = (4 * w + nt) * 16 + c16;
          float b1 = ff1_b[l * 256 + col];
#pragma unroll
          for (int mt6 = 0; mt6 < 6; ++mt6)
#pragma unroll
            for (int r = 0; r < 4; ++r) {
              int rloc = (mt6 >= 3 ? mt6 - 3 : mt6) * 16 + quad * 4 + r;
              int row = mt6 * 16 + quad * 4 + r;
              float v = fmaxf(fa[j][mt6][r] + b1, 0.f);
              hbf[row * 264 + col] = (__bf16)(rloc < NN_ ? v : 0.f);
            }
        }
      }
    }
    __syncthreads();

    // === FF2 + residual ===
    {
      const __bf16* f2W = wb + WB_FF2 + l * 128 * 256;
      const __bf16* Bs[2] = { f2W + ((2 * w) * 16 + c16) * 256, f2W + ((2 * w + 1) * 16 + c16) * 256 };
      f32x4 fa[2][6];
      gemm6xN<2, 8>(hbf, 264, Bs, c16, quad, fa);
#pragma unroll
      for (int nt = 0; nt < 2; ++nt) {
        float fb2 = ff2_b[l * 128 + (2 * w + nt) * 16 + c16];
#pragma unroll
        for (int mt6 = 0; mt6 < 6; ++mt6)
#pragma unroll
          for (int r = 0; r < 4; ++r) res[mt6][nt][r] += fa[nt][mt6][r] + fb2;
      }
    }
    ln_update(res, ln2_g + l * 128, ln2_b + l * 128, xbf, part, statsA, statsB, tid, w, c16, quad);
  }

  // ---- stage out: x_final (bf16) -> ws X, both trees ----
  {
    for (int c = tid; c < 1344; c += 256) {
      int tree = c >= 672 ? 1 : 0;
      int cc = c - tree * 672;
      int row = cc >> 4, co = (cc & 15) * 8;
      __bf16* Xf = Xg + (size_t)(f0 + tree) * 5376;
      *(bf16x8*)(Xf + row * 128 + co) = ld8(xbf + (tree * 48 + row) * 136 + co);
    }
  }
}

// ---------------- output projection + final LN, K split 4-way, 6-deep pipeline ----------------
__global__ __launch_bounds__(1024) void wout_k(const __bf16* __restrict__ X,
                                               const __bf16* __restrict__ Wb,
                                               const float* __restrict__ b_out,
                                               const float* __restrict__ lnf_g,
                                               const float* __restrict__ lnf_b,
                                               float* __restrict__ out) {
  const int blk = blockIdx.x, tid = threadIdx.x;
  const int lane = tid & 63, w2 = tid >> 6, wc = w2 & 3, kh = w2 >> 2;  // wc 0..3, kh 0..3
  const int c16 = lane & 15, quad = lane >> 4;
  __shared__ float cout[64 * 132];
  f32x4 acc0{0,0,0,0}, acc1{0,0,0,0};
  const __bf16* Ar = X + (size_t)(blk * 16 + c16) * 5376 + kh * 1344;
  const __bf16* B0 = Wb + (size_t)((2 * wc) * 16 + c16) * 5376 + kh * 1344;
  const __bf16* B1 = Wb + (size_t)((2 * wc + 1) * 16 + c16) * 5376 + kh * 1344;
  bf16x8 ab[6], b0b[6], b1b[6];
#pragma unroll
  for (int d = 0; d < 6; ++d) {
    int ko = d * 32 + quad * 8;
    ab[d] = ld8(Ar + ko); b0b[d] = ld8(B0 + ko); b1b[d] = ld8(B1 + ko);
  }
#pragma unroll
  for (int ks = 0; ks < 42; ++ks) {
    const int cur = ks % 6;
    acc0 = MFMA(ab[cur], b0b[cur], acc0);
    acc1 = MFMA(ab[cur], b1b[cur], acc1);
    if (ks + 6 < 42) {
      int ko = (ks + 6) * 32 + quad * 8;
      ab[cur] = ld8(Ar + ko); b0b[cur] = ld8(B0 + ko); b1b[cur] = ld8(B1 + ko);
    }
  }
#pragma unroll
  for (int nt = 0; nt < 2; ++nt) {
    f32x4 av = nt ? acc1 : acc0;
#pragma unroll
    for (int r = 0; r < 4; ++r) cout[(kh * 16 + quad * 4 + r) * 132 + (2 * wc + nt) * 16 + c16] = av[r];
  }
  __syncthreads();
  if (w2 < 4) {
#pragma unroll
    for (int rr = 0; rr < 4; ++rr) {
      int row = w2 * 4 + rr;
      float v0 = cout[row * 132 + lane] + cout[(16 + row) * 132 + lane] +
                 cout[(32 + row) * 132 + lane] + cout[(48 + row) * 132 + lane] + b_out[lane];
      float v1 = cout[row * 132 + 64 + lane] + cout[(16 + row) * 132 + 64 + lane] +
                 cout[(32 + row) * 132 + 64 + lane] + cout[(48 + row) * 132 + 64 + lane] + b_out[64 + lane];
      float s = v0 + v1, ss = v0 * v0 + v1 * v1;
#pragma unroll
      for (int m = 1; m < 64; m <<= 1) { s += __shfl_xor(s, m); ss += __shfl_xor(ss, m); }
      float mu = s * 0.0078125f;
      float var = fmaxf(ss * 0.0078125f - mu * mu, 0.f);
      float rs = rsqrtf(var + 1e-5f);
      size_t o = (size_t)(blk * 16 + row) * 128;
      out[o + lane] = (v0 - mu) * rs * lnf_g[lane] + lnf_b[lane];
      out[o + 64 + lane] = (v1 - mu) * rs * lnf_g[64 + lane] + lnf_b[64 + lane];
    }
  }
}

extern "C" void kernel_launch(void* const* d_in, const int* in_sizes, int n_in,
                              void* d_out, int out_size, void* d_ws, size_t ws_size,
                              hipStream_t stream) {
  const float* forest     = (const float*)d_in[0];
  const int*   adjacency  = (const int*)d_in[1];
  const int*   node_order = (const int*)d_in[2];
  const float* W_in       = (const float*)d_in[3];
  const float* b_in       = (const float*)d_in[4];
  const float* qkv_b      = (const float*)d_in[6];
  const float* ao_b       = (const float*)d_in[8];
  const float* ff1_b      = (const float*)d_in[10];
  const float* ff2_b      = (const float*)d_in[12];
  const float* ln1_g      = (const float*)d_in[13];
  const float* ln1_b      = (const float*)d_in[14];
  const float* ln2_g      = (const float*)d_in[15];
  const float* ln2_b      = (const float*)d_in[16];
  const float* b_out      = (const float*)d_in[18];
  const float* lnf_g      = (const float*)d_in[19];
  const float* lnf_b      = (const float*)d_in[20];
  __bf16* wb = (__bf16*)d_ws;
  float* out = (float*)d_out;

  prep_bf16<<<dim3(PREP_N / 256), dim3(256), 0, stream>>>(
      W_in, (const float*)d_in[5], (const float*)d_in[7], (const float*)d_in[9],
      (const float*)d_in[11], (const float*)d_in[17], wb);
  tree_enc<<<dim3(FB_ / 2), dim3(256), 0, stream>>>(forest, adjacency, node_order, b_in, qkv_b,
                                                    ao_b, ff1_b, ff2_b, ln1_g, ln1_b, ln2_g,
                                                    ln2_b, wb, wb + WB_X);
  wout_k<<<dim3(FB_ / 16), dim3(1024), 0, stream>>>(wb + WB_X, wb + WB_WOUT, b_out, lnf_g, lnf_b,
                                                    out);
}